// Round 8
// baseline (467.938 us; speedup 1.0000x reference)
//
#include <hip/hip_runtime.h>
#include <hip/hip_bf16.h>
#include <math.h>

typedef __bf16 bf16;
typedef __bf16 bf16x8 __attribute__((ext_vector_type(8)));
typedef __bf16 bf16x4 __attribute__((ext_vector_type(4)));
typedef float f32x4 __attribute__((ext_vector_type(4)));
typedef float f32x16 __attribute__((ext_vector_type(16)));

#define MFMA16(a, b, c) __builtin_amdgcn_mfma_f32_16x16x32_bf16((a), (b), (c), 0, 0, 0)
#define MFMA32(a, b, c) __builtin_amdgcn_mfma_f32_32x32x16_bf16((a), (b), (c), 0, 0, 0)

#define N_NODES 4096
#define C_DIM   256
#define E_EDGES 131072
#define APAD    280   // LDS A-row stride (elements): 560B, 16B-aligned
#define TPAD    264   // Trow stride (floats)
#define ETILES  4     // tiles per persistent edge_gemm block

// ---------------------------------------------------------------------------
// dtype helpers: inputs may be fp32 (per reference) or bf16 (per dataset).
// ---------------------------------------------------------------------------
__device__ __forceinline__ float ldf(const void* p, int i, bool f32) {
    return f32 ? ((const float*)p)[i] : (float)((const bf16*)p)[i];
}

__device__ __forceinline__ bf16x8 ld8(const void* base, size_t off, bool f32) {
    if (f32) {
        const float* p = (const float*)base + off;
        float4 a = *(const float4*)p;
        float4 b = *(const float4*)(p + 4);
        bf16x8 r;
        r[0] = (bf16)a.x; r[1] = (bf16)a.y; r[2] = (bf16)a.z; r[3] = (bf16)a.w;
        r[4] = (bf16)b.x; r[5] = (bf16)b.y; r[6] = (bf16)b.z; r[7] = (bf16)b.w;
        return r;
    }
    return *(const bf16x8*)((const bf16*)base + off);
}

// packed f32->bf16 pair (no builtin on gfx950; RNE)
__device__ __forceinline__ unsigned cvtpk(float a, float b) {
    unsigned r;
    asm("v_cvt_pk_bf16_f32 %0, %1, %2" : "=v"(r) : "v"(a), "v"(b));
    return r;
}
// swap hi-32-lanes of a with lo-32-lanes of b (both modified)
__device__ __forceinline__ void pl32swap(unsigned &a, unsigned &b) {
    asm volatile("v_permlane32_swap_b32 %0, %1" : "+v"(a), "+v"(b));
}

union PW { unsigned u[4]; bf16x8 v; };

__global__ __launch_bounds__(64) void detect_dtype(const void* x, int* flag)
{
    const bf16* xb = (const bf16*)x;
    int tid = threadIdx.x;
    int bad = 0;
    for (int i = tid; i < 4096; i += 64) {
        float v = fabsf((float)xb[i]);
        if (!(v >= 1e-6f && v <= 100.0f)) bad++;
    }
#pragma unroll
    for (int m = 1; m < 64; m <<= 1) bad += __shfl_xor(bad, m);
    if (tid == 0) *flag = (bad > 400) ? 1 : 0;
}

__global__ __launch_bounds__(256) void convert_inputs(
    const void* s0, const void* s1, const void* s2, const void* s3, const void* s4,
    bf16* dst, const int* flag)
{
    int idx = blockIdx.x * 256 + threadIdx.x;  // 6400 blocks -> 1638400
    const void* src; int local;
    if (idx < 1048576)      { src = s0; local = idx; }
    else if (idx < 1245184) { src = s1; local = idx - 1048576; }
    else if (idx < 1310720) { src = s2; local = idx - 1245184; }
    else if (idx < 1507328) { src = s3; local = idx - 1310720; }
    else                    { src = s4; local = idx - 1507328; }
    if (*flag) dst[idx] = (bf16)(((const float*)src)[local]);
    else ((unsigned short*)dst)[idx] = ((const unsigned short*)src)[local];
}

// ---------------------------------------------------------------------------
// CSR build
// ---------------------------------------------------------------------------
__global__ __launch_bounds__(256) void edge_hist(
    const int* __restrict__ ecol, int* __restrict__ counts)
{
    int e = blockIdx.x * 256 + threadIdx.x;
    atomicAdd(&counts[ecol[e]], 1);
}

__global__ __launch_bounds__(256) void edge_scan(
    const int* __restrict__ counts, int* __restrict__ offsets,
    int* __restrict__ cursor)
{
    __shared__ int part[256];
    __shared__ int pref[257];
    int t = threadIdx.x;
    int base = t * 16;
    int s = 0;
#pragma unroll
    for (int i = 0; i < 16; ++i) s += counts[base + i];
    part[t] = s;
    __syncthreads();
    if (t == 0) {
        int run = 0;
        for (int i = 0; i < 256; ++i) { pref[i] = run; run += part[i]; }
        pref[256] = run;
    }
    __syncthreads();
    int off = pref[t];
#pragma unroll
    for (int i = 0; i < 16; ++i) {
        offsets[base + i] = off;
        cursor[base + i]  = off;
        off += counts[base + i];
    }
    if (t == 255) offsets[4096] = off;
}

// Also writes the inverse permutation epos[e] = CSR slot of edge e, so the
// edge GEMM can emit rows directly in CSR order (node_ln then streams them).
__global__ __launch_bounds__(256) void edge_scatter(
    const int* __restrict__ ecol, int* __restrict__ cursor,
    int* __restrict__ eid, int* __restrict__ epos)
{
    int e = blockIdx.x * 256 + threadIdx.x;
    int pos = atomicAdd(&cursor[ecol[e]], 1);
    eid[pos] = e;
    epos[e] = pos;
}

// ---------------------------------------------------------------------------
// Generic GEMM: C[m][n] = sum_k A[m][k] * W[n][k] + bias[n] (+ resid)
// ---------------------------------------------------------------------------
__global__ __launch_bounds__(256) void gemm_bt(
    const bf16* __restrict__ A, int lda,
    const bf16* __restrict__ W, int ldw,
    const void* __restrict__ bias,
    void* __restrict__ Cout, int ldc, int c_f32,
    const bf16* __restrict__ resid, int ldr,
    int K, const int* __restrict__ flag)
{
    const bool f32 = (*flag != 0);
    const int wave = threadIdx.x >> 6;
    const int lane = threadIdx.x & 63;
    const int quad = lane >> 4;
    const int l16  = lane & 15;
    const int m_base = blockIdx.x * 32;
    const int n_base = blockIdx.y * 256 + wave * 64;

    const bf16* a0p = A + (size_t)(m_base + l16) * lda + quad * 8;
    const bf16* a1p = a0p + (size_t)16 * lda;
    const bf16* wp  = W + (size_t)(n_base + l16) * ldw + quad * 8;

    f32x4 acc[2][4] = {};
    for (int k = 0; k < K; k += 32) {
        bf16x8 a0 = *(const bf16x8*)(a0p + k);
        bf16x8 a1 = *(const bf16x8*)(a1p + k);
#pragma unroll
        for (int nt = 0; nt < 4; ++nt) {
            bf16x8 b = *(const bf16x8*)(wp + (size_t)nt * 16 * ldw + k);
            acc[0][nt] = MFMA16(a0, b, acc[0][nt]);
            acc[1][nt] = MFMA16(a1, b, acc[1][nt]);
        }
    }
#pragma unroll
    for (int mt = 0; mt < 2; ++mt) {
#pragma unroll
        for (int nt = 0; nt < 4; ++nt) {
            int col = n_base + nt * 16 + l16;
            float bv = bias ? ldf(bias, col, f32) : 0.0f;
#pragma unroll
            for (int r = 0; r < 4; ++r) {
                int row = m_base + mt * 16 + quad * 4 + r;
                float v = acc[mt][nt][r] + bv;
                if (resid) v += (float)resid[(size_t)row * ldr + col];
                if (c_f32) ((float*)Cout)[(size_t)row * ldc + col] = v;
                else       ((bf16*)Cout)[(size_t)row * ldc + col] = (bf16)v;
            }
        }
    }
}

// ---------------------------------------------------------------------------
// U/V precompute in ONE launch: grid (128, 2). y=0: U = x @ ew[:, 0:256]^T;
// y=1: V = x @ ew[:, 256:512]^T.
// ---------------------------------------------------------------------------
__global__ __launch_bounds__(256) void gemm_uv(
    const bf16* __restrict__ x, const bf16* __restrict__ ew,
    bf16* __restrict__ U, bf16* __restrict__ V)
{
    const int wave = threadIdx.x >> 6;
    const int lane = threadIdx.x & 63;
    const int quad = lane >> 4;
    const int l16  = lane & 15;
    const int m_base = blockIdx.x * 32;
    bf16* dst = blockIdx.y ? V : U;
    const bf16* W = ew + blockIdx.y * 256;

    const bf16* a0p = x + (size_t)(m_base + l16) * 256 + quad * 8;
    const bf16* a1p = a0p + (size_t)16 * 256;
    const bf16* wp  = W + (size_t)(wave * 64 + l16) * 768 + quad * 8;

    f32x4 acc[2][4] = {};
#pragma unroll
    for (int kk = 0; kk < 8; ++kk) {
        int k = kk * 32;
        bf16x8 a0 = *(const bf16x8*)(a0p + k);
        bf16x8 a1 = *(const bf16x8*)(a1p + k);
#pragma unroll
        for (int nt = 0; nt < 4; ++nt) {
            bf16x8 b = *(const bf16x8*)(wp + (size_t)nt * 16 * 768 + k);
            acc[0][nt] = MFMA16(a0, b, acc[0][nt]);
            acc[1][nt] = MFMA16(a1, b, acc[1][nt]);
        }
    }
#pragma unroll
    for (int mt = 0; mt < 2; ++mt)
#pragma unroll
        for (int nt = 0; nt < 4; ++nt) {
            int col = wave * 64 + nt * 16 + l16;
#pragma unroll
            for (int r = 0; r < 4; ++r) {
                int row = m_base + mt * 16 + quad * 4 + r;
                dst[(size_t)row * 256 + col] = (bf16)acc[mt][nt][r];
            }
        }
}

// ---------------------------------------------------------------------------
// Plain V transpose: vt[c][n] = V[n][c]  (V = qkv cols 512..768)
// ---------------------------------------------------------------------------
__global__ __launch_bounds__(256) void transpose_v(
    const bf16* __restrict__ qkv, bf16* __restrict__ vt)
{
    __shared__ bf16 t[32][65];
    const int n0 = blockIdx.x * 64;
    const int c0 = blockIdx.y * 32;
    const int tid = threadIdx.x;
    {
        int cl = tid & 31, nl = tid >> 5;
#pragma unroll
        for (int p = 0; p < 8; ++p) {
            int n = nl + p * 8;
            t[cl][n] = qkv[(size_t)(n0 + n) * 768 + 512 + c0 + cl];
        }
    }
    __syncthreads();
    {
        int nn = tid & 63, cc = tid >> 6;
#pragma unroll
        for (int p = 0; p < 8; ++p) {
            int c = cc + p * 4;
            vt[(size_t)(c0 + c) * 4096 + n0 + nn] = t[c][nn];
        }
    }
}

// ---------------------------------------------------------------------------
// Flash attention v3: 32x32 swapped-operand MFMA (unchanged - works).
// ---------------------------------------------------------------------------
__global__ __launch_bounds__(256) void attn_kernel(
    const bf16* __restrict__ qkv,
    const bf16* __restrict__ vt,
    bf16* __restrict__ ctx)
{
    __shared__ float oL[4][32][33];
    __shared__ float mS[4][32];
    __shared__ float lS[4][32];
    const int tid  = threadIdx.x;
    const int wave = tid >> 6;
    const int lane = tid & 63;
    const int l32  = lane & 31;
    const int hl   = lane >> 5;
    const int h  = blockIdx.x >> 7;
    const int qt = blockIdx.x & 127;

    const float csc = 1.4426950408889634f * 0.17677669529663687f;

    const bf16* qrow = qkv + (size_t)(qt * 32 + l32) * 768 + h * 32 + hl * 8;
    bf16x8 qf1 = *(const bf16x8*)qrow;
    bf16x8 qf2 = *(const bf16x8*)(qrow + 16);

    const bf16* kbp = qkv + 256 + h * 32 + hl * 8;
    const bf16* vrp = vt + (size_t)(h * 32 + l32) * 4096 + hl * 8;

    float mrun = -INFINITY, msc = -INFINITY, lacc = 0.f;
    f32x16 oacc = {};
    const f32x16 z16 = {};

    const int kbeg = wave * 1024;
    for (int k0 = kbeg; k0 < kbeg + 1024; k0 += 32) {
        const bf16* kp = kbp + (size_t)(k0 + l32) * 768;
        bf16x8 kf1 = *(const bf16x8*)kp;
        bf16x8 kf2 = *(const bf16x8*)(kp + 16);
        bf16x8 vf1 = *(const bf16x8*)(vrp + k0);
        bf16x8 vf2 = *(const bf16x8*)(vrp + k0 + 16);

        f32x16 s = MFMA32(kf1, qf1, z16);
        s = MFMA32(kf2, qf2, s);

        float a0 = fmaxf(fmaxf(s[0], s[1]), fmaxf(s[2], s[3]));
        float a1 = fmaxf(fmaxf(s[4], s[5]), fmaxf(s[6], s[7]));
        float a2 = fmaxf(fmaxf(s[8], s[9]), fmaxf(s[10], s[11]));
        float a3 = fmaxf(fmaxf(s[12], s[13]), fmaxf(s[14], s[15]));
        float tm = fmaxf(fmaxf(a0, a1), fmaxf(a2, a3));
        tm = fmaxf(tm, __shfl_xor(tm, 32));

        if (__any(tm > mrun)) {
            float nm = fmaxf(mrun, tm);
            float nmsc = nm * csc;
            float al = exp2f(msc - nmsc);
            mrun = nm; msc = nmsc;
            lacc *= al;
#pragma unroll
            for (int i = 0; i < 16; ++i) oacc[i] *= al;
        }

        float p[16];
#pragma unroll
        for (int i = 0; i < 16; ++i) {
            p[i] = exp2f(__builtin_fmaf(s[i], csc, -msc));
            lacc += p[i];
        }

        unsigned w0 = cvtpk(p[0], p[1]),  w1 = cvtpk(p[2], p[3]);
        unsigned w2 = cvtpk(p[4], p[5]),  w3 = cvtpk(p[6], p[7]);
        unsigned w4 = cvtpk(p[8], p[9]),  w5 = cvtpk(p[10], p[11]);
        unsigned w6 = cvtpk(p[12], p[13]), w7 = cvtpk(p[14], p[15]);
        pl32swap(w0, w2); pl32swap(w1, w3);
        pl32swap(w4, w6); pl32swap(w5, w7);
        PW f1; f1.u[0] = w0; f1.u[1] = w1; f1.u[2] = w2; f1.u[3] = w3;
        PW f2; f2.u[0] = w4; f2.u[1] = w5; f2.u[2] = w6; f2.u[3] = w7;

        oacc = MFMA32(vf1, f1.v, oacc);
        oacc = MFMA32(vf2, f2.v, oacc);
    }

    lacc += __shfl_xor(lacc, 32);
    if (hl == 0) { mS[wave][l32] = mrun; lS[wave][l32] = lacc; }
#pragma unroll
    for (int i = 0; i < 16; ++i) {
        int d = (i & 3) + 8 * (i >> 2) + 4 * hl;
        oL[wave][l32][d] = oacc[i];
    }
    __syncthreads();
    {
        int q = tid >> 3, d0 = (tid & 7) * 4;
        float m0 = mS[0][q], m1 = mS[1][q], m2 = mS[2][q], m3 = mS[3][q];
        float ms = fmaxf(fmaxf(m0, m1), fmaxf(m2, m3));
        float f0 = exp2f((m0 - ms) * csc), f1 = exp2f((m1 - ms) * csc);
        float f2 = exp2f((m2 - ms) * csc), f3 = exp2f((m3 - ms) * csc);
        float ls = lS[0][q] * f0 + lS[1][q] * f1 + lS[2][q] * f2 + lS[3][q] * f3;
        float inv = 1.0f / ls;
        bf16x4 o4;
#pragma unroll
        for (int i = 0; i < 4; ++i) {
            int d = d0 + i;
            float v = (oL[0][q][d] * f0 + oL[1][q][d] * f1 +
                       oL[2][q][d] * f2 + oL[3][q][d] * f3) * inv;
            o4[i] = (bf16)v;
        }
        *(bf16x4*)(ctx + (size_t)(qt * 32 + q) * 256 + h * 32 + d0) = o4;
    }
}

// ---------------------------------------------------------------------------
// Edge GEMM v5: persistent + pipelined. Grid 512 (2 blocks/CU resident),
// ETILES=4 tiles of 64 edges per block. Per tile: ISSUE next tile's A loads
// into registers BEFORE the K-loop (early-issue / late-write, T14), compute
// current tile from LDS (B per-k0 from L2), epilogue (swizzled Trow,
// coalesced CSR-slot stores), then ds_write the prefetched regs into Asm
// (vmcnt wait lands here, hidden under ~3us of K+epilogue work). Breaks the
// phase-locked convoy (R4/R6/R7 all ~93us with every pipe idle): memory
// issue now structurally interleaves with compute within each block.
// ---------------------------------------------------------------------------
__global__ __launch_bounds__(256) void edge_gemm(
    const void* __restrict__ eattr,
    const bf16* __restrict__ ew,          // [256][768]; cols 512.. used
    const void* __restrict__ eb,
    const int* __restrict__ epos,
    bf16* __restrict__ msgpre, const int* __restrict__ flag)
{
    __shared__ char smem[64 * APAD * 2];          // 35840 B (Asm / Trow overlay)
    bf16* Asm = (bf16*)smem;                      // [64][APAD]
    float (*Trow)[TPAD] = (float(*)[TPAD])smem;   // epilogue reuse: 32 x 264 f32

    const bool f32 = (*flag != 0);
    const int tid  = threadIdx.x;
    const int wave = tid >> 6;
    const int lane = tid & 63;
    const int quad = lane >> 4;
    const int l16  = lane & 15;
    const int srow  = tid >> 2;          // staging row 0..63
    const int cbase = (tid & 3) * 64;    // staging col base

    const bf16* wp = ew + (size_t)(wave * 64 + l16) * 768 + 512 + quad * 8;

    float ebv[4];
#pragma unroll
    for (int nt = 0; nt < 4; ++nt)
        ebv[nt] = ldf(eb, wave * 64 + nt * 16 + l16, f32);

    const int tile0 = blockIdx.x * ETILES;

    // prefetch registers for the staging rows (128B/thread)
    bf16x8 areg[8];

    // ---- initial tile load -> regs -> LDS ----
    {
        if (!f32) {
            const bf16* src = (const bf16*)eattr +
                (size_t)(tile0 * 64 + srow) * 256 + cbase;
#pragma unroll
            for (int j = 0; j < 8; ++j) areg[j] = *(const bf16x8*)(src + j * 8);
        } else {
            const float* src = (const float*)eattr +
                (size_t)(tile0 * 64 + srow) * 256 + cbase;
#pragma unroll
            for (int j = 0; j < 8; ++j) {
                float4 a = *(const float4*)(src + j * 8);
                float4 b = *(const float4*)(src + j * 8 + 4);
                bf16x8 r;
                r[0] = (bf16)a.x; r[1] = (bf16)a.y; r[2] = (bf16)a.z; r[3] = (bf16)a.w;
                r[4] = (bf16)b.x; r[5] = (bf16)b.y; r[6] = (bf16)b.z; r[7] = (bf16)b.w;
                areg[j] = r;
            }
        }
        bf16* dst = Asm + srow * APAD + cbase;
#pragma unroll
        for (int j = 0; j < 8; ++j) *(bf16x8*)(dst + j * 8) = areg[j];
    }
    __syncthreads();

    for (int t = 0; t < ETILES; ++t) {
        const int e_base = (tile0 + t) * 64;

        // ---- EARLY-ISSUE next tile's A loads (results used after epilogue)
        if (t + 1 < ETILES) {
            if (!f32) {
                const bf16* src = (const bf16*)eattr +
                    (size_t)((tile0 + t + 1) * 64 + srow) * 256 + cbase;
#pragma unroll
                for (int j = 0; j < 8; ++j) areg[j] = *(const bf16x8*)(src + j * 8);
            } else {
                const float* src = (const float*)eattr +
                    (size_t)((tile0 + t + 1) * 64 + srow) * 256 + cbase;
#pragma unroll
                for (int j = 0; j < 8; ++j) {
                    float4 a = *(const float4*)(src + j * 8);
                    float4 b = *(const float4*)(src + j * 8 + 4);
                    bf16x8 r;
                    r[0] = (bf16)a.x; r[1] = (bf16)a.y; r[2] = (bf16)a.z; r[3] = (bf16)a.w;
                    r[4] = (bf16)b.x; r[5] = (bf16)b.y; r[6] = (bf16)b.z; r[7] = (bf16)b.w;
                    areg[j] = r;
                }
            }
        }

        // ---- K loop: B per-k0 from L2, A from LDS ----
        f32x4 acc[4][4] = {};
#pragma unroll
        for (int k0 = 0; k0 < 8; ++k0) {
            bf16x8 b[4];
#pragma unroll
            for (int nt = 0; nt < 4; ++nt)
                b[nt] = *(const bf16x8*)(wp + (size_t)nt * 16 * 768 + k0 * 32);
#pragma unroll
            for (int mt = 0; mt < 4; ++mt) {
                bf16x8 af = *(const bf16x8*)(Asm + (mt * 16 + l16) * APAD + k0 * 32 + quad * 8);
#pragma unroll
                for (int nt = 0; nt < 4; ++nt)
                    acc[mt][nt] = MFMA16(af, b[nt], acc[mt][nt]);
            }
        }

        // ---- epilogue: +eb -> swizzled Trow -> coalesced CSR-slot stores --
        for (int p = 0; p < 2; ++p) {
            __syncthreads();   // K-loop Asm reads done (p=0) / Trow WAR (p=1)
#pragma unroll
            for (int mtl = 0; mtl < 2; ++mtl) {
                int mt = p * 2 + mtl;
#pragma unroll
                for (int nt = 0; nt < 4; ++nt) {
                    int c = wave * 64 + nt * 16 + l16;
                    int cs = c ^ (((c >> 5) & 7) << 2);     // self-XOR swizzle
#pragma unroll
                    for (int r = 0; r < 4; ++r)
                        Trow[mtl * 16 + quad * 4 + r][cs] = acc[mt][nt][r] + ebv[nt];
                }
            }
            __syncthreads();
            {
                int row = tid >> 3;          // 0..31
                int seg = tid & 7;           // 32-col segment
                int ep = epos[e_base + p * 32 + row];
                const float* tr = Trow[row];
                const int t4 = (seg & 7) << 2;
                bf16* op = msgpre + (size_t)ep * 256 + seg * 32;
#pragma unroll
                for (int i = 0; i < 4; ++i) {
                    float4 a = *(const float4*)(tr + ((seg * 32 + i * 8) ^ t4));
                    float4 b = *(const float4*)(tr + ((seg * 32 + i * 8 + 4) ^ t4));
                    bf16x8 o;
                    o[0] = (bf16)a.x; o[1] = (bf16)a.y; o[2] = (bf16)a.z; o[3] = (bf16)a.w;
                    o[4] = (bf16)b.x; o[5] = (bf16)b.y; o[6] = (bf16)b.z; o[7] = (bf16)b.w;
                    *(bf16x8*)(op + i * 8) = o;
                }
            }
        }

        // ---- late-write the prefetched tile into Asm (vmcnt waits here) ----
        if (t + 1 < ETILES) {
            __syncthreads();   // p1 Trow reads done (Asm overlays Trow)
            bf16* dst = Asm + srow * APAD + cbase;
#pragma unroll
            for (int j = 0; j < 8; ++j) *(bf16x8*)(dst + j * 8) = areg[j];
            __syncthreads();
        }
    }
}

// ---------------------------------------------------------------------------
// Stage 2: per-node LN+ReLU+sum, fully streaming. Block = node; msgpre rows
// for the node are CONTIGUOUS (CSR order) -> full-wave 512B coalesced reads.
// ---------------------------------------------------------------------------
__global__ __launch_bounds__(256) void node_ln(
    const bf16* __restrict__ msgpre,
    const int* __restrict__ offsets, const int* __restrict__ eid,
    const int* __restrict__ erow,
    const bf16* __restrict__ U, const bf16* __restrict__ V,
    const void* __restrict__ g1, const void* __restrict__ b1,
    bf16* __restrict__ combined, const int* __restrict__ flag)
{
    __shared__ float accL[4][256];
    const bool f32 = (*flag != 0);
    const int wave = threadIdx.x >> 6;
    const int lane = threadIdx.x & 63;
    const int node = blockIdx.x;
    const int start = offsets[node];
    const int cnt   = offsets[node + 1] - start;

    float glv[4], blv[4], vv[4];
#pragma unroll
    for (int i = 0; i < 4; ++i) {
        glv[i] = ldf(g1, lane * 4 + i, f32);
        blv[i] = ldf(b1, lane * 4 + i, f32);
    }
    {
        bf16x4 v4 = *(const bf16x4*)(V + (size_t)node * 256 + lane * 4);
#pragma unroll
        for (int i = 0; i < 4; ++i) vv[i] = (float)v4[i];
    }

    float nacc[4] = {0.f, 0.f, 0.f, 0.f};
    for (int i = wave; i < cnt; i += 4) {
        int pos = start + i;
        int er = erow[eid[pos]];                       // wave-uniform scalars
        bf16x4 t4 = *(const bf16x4*)(msgpre + (size_t)pos * 256 + lane * 4);
        bf16x4 u4 = *(const bf16x4*)(U + (size_t)er * 256 + lane * 4);
        float val[4];
        float s = 0.f, q = 0.f;
#pragma unroll
        for (int j = 0; j < 4; ++j) {
            val[j] = (float)t4[j] + (float)u4[j] + vv[j];
            s += val[j];
            q = __builtin_fmaf(val[j], val[j], q);
        }
#pragma unroll
        for (int msk = 1; msk < 64; msk <<= 1) {
            s += __shfl_xor(s, msk);
            q += __shfl_xor(q, msk);
        }
        float mean = s * (1.0f / 256.0f);
        float var  = q * (1.0f / 256.0f) - mean * mean;
        float rstd = rsqrtf(var + 1e-5f);
#pragma unroll
        for (int j = 0; j < 4; ++j)
            nacc[j] += fmaxf((val[j] - mean) * rstd * glv[j] + blv[j], 0.0f);
    }
#pragma unroll
    for (int j = 0; j < 4; ++j) accL[wave][lane * 4 + j] = nacc[j];
    __syncthreads();
    if (wave == 0) {
        bf16x4 o4;
#pragma unroll
        for (int j = 0; j < 4; ++j) {
            int c = lane * 4 + j;
            float s = (accL[0][c] + accL[1][c]) + (accL[2][c] + accL[3][c]);
            o4[j] = (bf16)s;
        }
        *(bf16x4*)(combined + (size_t)node * 512 + 256 + lane * 4) = o4;
    }
}

// ---------------------------------------------------------------------------
// Fallback (round-3 path) if ws too small for msgpre buffer.
// ---------------------------------------------------------------------------
__global__ __launch_bounds__(256) void edge_node(
    const bf16* __restrict__ x,
    const int* __restrict__ erow,
    const void* __restrict__ eattr,
    const bf16* __restrict__ ew,
    const void* __restrict__ eb,
    const void* __restrict__ g1, const void* __restrict__ b1,
    const int* __restrict__ offsets, const int* __restrict__ eid,
    bf16* __restrict__ combined, const int* __restrict__ flag)
{
    __shared__ float part[32][4][2];
    const bool f32 = (*flag != 0);
    const int wave = threadIdx.x >> 6;
    const int lane = threadIdx.x & 63;
    const int quad = lane >> 4;
    const int l16  = lane & 15;
    const int n = blockIdx.x;
    const int start = offsets[n];
    const int cnt   = offsets[n + 1] - start;

    float gv[4], bv[4], ebv[4];
#pragma unroll
    for (int nt = 0; nt < 4; ++nt) {
        int col = wave * 64 + nt * 16 + l16;
        gv[nt]  = ldf(g1, col, f32);
        bv[nt]  = ldf(b1, col, f32);
        ebv[nt] = ldf(eb, col, f32);
    }
    const bf16* wp = ew + (size_t)(wave * 64 + l16) * 768 + quad * 8;
    const bf16* xn = x + (size_t)n * 256 + quad * 8;

    f32x4 acc1[4] = {};
#pragma unroll
    for (int kk = 0; kk < 8; ++kk) {
        bf16x8 a = *(const bf16x8*)(xn + kk * 32);
#pragma unroll
        for (int nt = 0; nt < 4; ++nt) {
            bf16x8 b = *(const bf16x8*)(wp + (size_t)nt * 16 * 768 + 256 + kk * 32);
            acc1[nt] = MFMA16(a, b, acc1[nt]);
        }
    }
    float nacc[4] = {0.f, 0.f, 0.f, 0.f};
    for (int c0 = 0; c0 < cnt; c0 += 32) {
        int i0 = c0 + l16;      i0 = (i0 < cnt) ? i0 : 0;
        int i1 = c0 + 16 + l16; i1 = (i1 < cnt) ? i1 : 0;
        int e0 = eid[start + i0];
        int e1 = eid[start + i1];
        const bf16* xr0 = x + (size_t)erow[e0] * 256 + quad * 8;
        const bf16* xr1 = x + (size_t)erow[e1] * 256 + quad * 8;
        f32x4 acc[2][4];
#pragma unroll
        for (int nt = 0; nt < 4; ++nt) { acc[0][nt] = acc1[nt]; acc[1][nt] = acc1[nt]; }
#pragma unroll
        for (int kk = 0; kk < 8; ++kk) {
            bf16x8 a0 = *(const bf16x8*)(xr0 + kk * 32);
            bf16x8 a1 = *(const bf16x8*)(xr1 + kk * 32);
#pragma unroll
            for (int nt = 0; nt < 4; ++nt) {
                bf16x8 b = *(const bf16x8*)(wp + (size_t)nt * 16 * 768 + kk * 32);
                acc[0][nt] = MFMA16(a0, b, acc[0][nt]);
                acc[1][nt] = MFMA16(a1, b, acc[1][nt]);
            }
        }
#pragma unroll
        for (int kk = 0; kk < 8; ++kk) {
            int koff = quad * 8 + kk * 32;
            bf16x8 a0 = ld8(eattr, (size_t)e0 * 256 + koff, f32);
            bf16x8 a1 = ld8(eattr, (size_t)e1 * 256 + koff, f32);
#pragma unroll
            for (int nt = 0; nt < 4; ++nt) {
                bf16x8 b = *(const bf16x8*)(wp + (size_t)nt * 16 * 768 + 512 + kk * 32);
                acc[0][nt] = MFMA16(a0, b, acc[0][nt]);
                acc[1][nt] = MFMA16(a1, b, acc[1][nt]);
            }
        }
#pragma unroll
        for (int mt = 0; mt < 2; ++mt)
#pragma unroll
            for (int nt = 0; nt < 4; ++nt)
#pragma unroll
                for (int r = 0; r < 4; ++r) acc[mt][nt][r] += ebv[nt];
        float ps[2][4], pq[2][4];
#pragma unroll
        for (int mt = 0; mt < 2; ++mt)
#pragma unroll
            for (int r = 0; r < 4; ++r) {
                float s = 0.f, q = 0.f;
#pragma unroll
                for (int nt = 0; nt < 4; ++nt) {
                    float v = acc[mt][nt][r];
                    s += v; q += v * v;
                }
                ps[mt][r] = s; pq[mt][r] = q;
            }
#pragma unroll
        for (int msk = 1; msk < 16; msk <<= 1)
#pragma unroll
            for (int mt = 0; mt < 2; ++mt)
#pragma unroll
                for (int r = 0; r < 4; ++r) {
                    ps[mt][r] += __shfl_xor(ps[mt][r], msk);
                    pq[mt][r] += __shfl_xor(pq[mt][r], msk);
                }
        if (l16 == 0) {
#pragma unroll
            for (int mt = 0; mt < 2; ++mt)
#pragma unroll
                for (int r = 0; r < 4; ++r) {
                    part[mt * 16 + quad * 4 + r][wave][0] = ps[mt][r];
                    part[mt * 16 + quad * 4 + r][wave][1] = pq[mt][r];
                }
        }
        __syncthreads();
#pragma unroll
        for (int mt = 0; mt < 2; ++mt)
#pragma unroll
            for (int r = 0; r < 4; ++r) {
                int row = mt * 16 + quad * 4 + r;
                float s = part[row][0][0] + part[row][1][0] + part[row][2][0] + part[row][3][0];
                float q = part[row][0][1] + part[row][1][1] + part[row][2][1] + part[row][3][1];
                float mean = s * (1.0f / 256.0f);
                float var  = q * (1.0f / 256.0f) - mean * mean;
                float rstd = rsqrtf(var + 1e-5f);
                if ((c0 + row) < cnt) {
#pragma unroll
                    for (int nt = 0; nt < 4; ++nt) {
                        float val = (acc[mt][nt][r] - mean) * rstd * gv[nt] + bv[nt];
                        nacc[nt] += fmaxf(val, 0.0f);
                    }
                }
            }
        __syncthreads();
    }
#pragma unroll
    for (int nt = 0; nt < 4; ++nt) {
        nacc[nt] += __shfl_xor(nacc[nt], 16);
        nacc[nt] += __shfl_xor(nacc[nt], 32);
    }
    if (quad == 0) {
#pragma unroll
        for (int nt = 0; nt < 4; ++nt)
            combined[(size_t)n * 512 + 256 + wave * 64 + nt * 16 + l16] = (bf16)nacc[nt];
    }
}

// ---------------------------------------------------------------------------
// Fused output projection + bias + residual + LayerNorm2. M=16 rows/block
// (grid 256 = full GPU), K=512.
// ---------------------------------------------------------------------------
__global__ __launch_bounds__(256) void gemm_ln(
    const bf16* __restrict__ A,          // combined [4096][512]
    const bf16* __restrict__ W,          // ow [256][512]
    const void* __restrict__ bias,       // o_b
    const bf16* __restrict__ resid,      // x_bf [4096][256]
    const void* __restrict__ g, const void* __restrict__ bb,
    void* __restrict__ out, const int* __restrict__ flag)
{
    __shared__ float stats[16][4][2];
    const bool f32 = (*flag != 0);
    const int wave = threadIdx.x >> 6;
    const int lane = threadIdx.x & 63;
    const int quad = lane >> 4;
    const int l16  = lane & 15;
    const int m_base = blockIdx.x * 16;

    const bf16* ap = A + (size_t)(m_base + l16) * 512 + quad * 8;
    const bf16* wp = W + (size_t)(wave * 64 + l16) * 512 + quad * 8;

    f32x4 acc[4] = {};
#pragma unroll
    for (int kk = 0; kk < 16; ++kk) {
        int k = kk * 32;
        bf16x8 a = *(const bf16x8*)(ap + k);
#pragma unroll
        for (int nt = 0; nt < 4; ++nt) {
            bf16x8 b = *(const bf16x8*)(wp + (size_t)nt * 16 * 512 + k);
            acc[nt] = MFMA16(a, b, acc[nt]);
        }
    }
    float s[4] = {}, q[4] = {};
#pragma unroll
    for (int nt = 0; nt < 4; ++nt) {
        int col = wave * 64 + nt * 16 + l16;
        float bv = ldf(bias, col, f32);
#pragma unroll
        for (int r = 0; r < 4; ++r) {
            int row = m_base + quad * 4 + r;
            float v = acc[nt][r] + bv + (float)resid[(size_t)row * 256 + col];
            acc[nt][r] = v;
            s[r] += v;
            q[r] = __builtin_fmaf(v, v, q[r]);
        }
    }
#pragma unroll
    for (int msk = 1; msk < 16; msk <<= 1)
#pragma unroll
        for (int r = 0; r < 4; ++r) {
            s[r] += __shfl_xor(s[r], msk);
            q[r] += __shfl_xor(q[r], msk);
        }
    if (l16 == 0) {
#pragma unroll
        for (int r = 0; r < 4; ++r) {
            stats[quad * 4 + r][wave][0] = s[r];
            stats[quad * 4 + r][wave][1] = q[r];
        }
    }
    __syncthreads();
#pragma unroll
    for (int r = 0; r < 4; ++r) {
        int row16 = quad * 4 + r;
        float ss = (stats[row16][0][0] + stats[row16][1][0]) +
                   (stats[row16][2][0] + stats[row16][3][0]);
        float qq = (stats[row16][0][1] + stats[row16][1][1]) +
                   (stats[row16][2][1] + stats[row16][3][1]);
        float mean = ss * (1.0f / 256.0f);
        float var  = qq * (1.0f / 256.0f) - mean * mean;
        float rstd = rsqrtf(var + 1e-5f);
        int row = m_base + row16;
#pragma unroll
        for (int nt = 0; nt < 4; ++nt) {
            int col = wave * 64 + nt * 16 + l16;
            float o = (acc[nt][r] - mean) * rstd * ldf(g, col, f32) + ldf(bb, col, f32);
            if (f32) ((float*)out)[(size_t)row * 256 + col] = o;
            else     ((bf16*)out)[(size_t)row * 256 + col] = (bf16)o;
        }
    }
}

// ---------------------------------------------------------------------------
extern "C" void kernel_launch(void* const* d_in, const int* in_sizes, int n_in,
                              void* d_out, int out_size, void* d_ws, size_t ws_size,
                              hipStream_t stream)
{
    const void* x_raw  = d_in[0];
    const int*  eidx   = (const int*)d_in[1];
    const void* eattr  = d_in[2];
    const void* in_w   = d_in[3];
    const void* in_b   = d_in[4];
    const void* ao_w   = d_in[5];
    const void* ao_b   = d_in[6];
    const void* e_w    = d_in[7];
    const void* e_b    = d_in[8];
    const void* g1     = d_in[9];
    const void* b1     = d_in[10];
    const void* o_w    = d_in[11];
    const void* o_b    = d_in[12];
    const void* g2     = d_in[13];
    const void* b2     = d_in[14];

    char* ws = (char*)d_ws;
    bf16*  qkv      = (bf16*)(ws);               // 6291456 B
    bf16*  vt       = (bf16*)(ws + 6291456);     // 2097152 B
    bf16*  ctx      = (bf16*)(ws + 8388608);     // 2097152 B
    bf16*  combined = (bf16*)(ws + 10485760);    // 4194304 B
    int*   counts   = (int*)(ws + 14680064);     // 16384 B
    int*   offsets  = (int*)(ws + 14696448);     // 16388 B
    int*   cursor   = (int*)(ws + 14712848);     // 16384 B
    int*   eid      = (int*)(ws + 14729232);     // 524288 B
    int*   epos     = (int*)(ws + 15253520);     // 524288 B
    bf16*  U        = (bf16*)(ws + 18874368);    // 2097152 B
    bf16*  V        = (bf16*)(ws + 20971520);    // 2097152 B
    bf16*  canon    = (bf16*)(ws + 23068672);    // 3276800 B
    int*   flag     = (int*)(ws + 26345472);     // 4 B
    bf16*  msgpre   = (bf16*)(ws + 26345728);    // 67108864 B -> end 93454592

    const size_t WS_NEEDED = 93454592;

    bf16* x_bf   = canon;
    bf16* inw_bf = canon + 1048576;
    bf16* aow_bf = canon + 1245184;
    bf16* ew_bf  = canon + 1310720;
    bf16* ow_bf  = canon + 1507328;

    const int* erow = eidx;
    const int* ecol = eidx + E_EDGES;

    detect_dtype<<<dim3(1), 64, 0, stream>>>(x_raw, flag);
    convert_inputs<<<dim3(6400), 256, 0, stream>>>(x_raw, in_w, ao_w, e_w, o_w,
                                                   canon, flag);
    // CSR build (+ inverse permutation epos)
    hipMemsetAsync(counts, 0, 16384, stream);
    edge_hist<<<dim3(E_EDGES / 256), 256, 0, stream>>>(ecol, counts);
    edge_scan<<<dim3(1), 256, 0, stream>>>(counts, offsets, cursor);
    edge_scatter<<<dim3(E_EDGES / 256), 256, 0, stream>>>(ecol, cursor, eid, epos);

    // node-level precomputes for the edge MLP: U = x@W0^T, V = x@W1^T (1 launch)
    gemm_uv<<<dim3(128, 2), 256, 0, stream>>>(x_bf, ew_bf, U, V);

    // qkv = x @ in_proj_w^T + in_proj_b
    gemm_bt<<<dim3(128, 3), 256, 0, stream>>>(x_bf, 256, inw_bf, 256, in_b,
                                              qkv, 768, 0, nullptr, 0, 256, flag);
    transpose_v<<<dim3(64, 8), 256, 0, stream>>>(qkv, vt);
    attn_kernel<<<dim3(1024), 256, 0, stream>>>(qkv, vt, ctx);
    gemm_bt<<<dim3(128, 1), 256, 0, stream>>>(ctx, 256, aow_bf, 256, ao_b,
                                              combined, 512, 0, nullptr, 0, 256, flag);
    if (ws_size >= WS_NEEDED) {
        // stage 1: persistent pipelined GEMM, rows emitted in CSR order
        edge_gemm<<<dim3(E_EDGES / 64 / ETILES), 256, 0, stream>>>(eattr, ew_bf, e_b,
                                                                   epos, msgpre, flag);
        // stage 2: per-node LN+ReLU+sum over contiguous CSR rows
        node_ln<<<dim3(N_NODES), 256, 0, stream>>>(msgpre, offsets, eid, erow,
                                                   U, V, g1, b1, combined, flag);
    } else {
        edge_node<<<dim3(N_NODES), 256, 0, stream>>>(x_bf, erow, eattr,
                                                     ew_bf, e_b, g1, b1,
                                                     offsets, eid, combined, flag);
    }
    // fused out-proj + residual + LN2 -> d_out
    gemm_ln<<<dim3(256), 256, 0, stream>>>(combined, ow_bf, o_b, x_bf,
                                           g2, b2, d_out, flag);
}

// Round 9
// 457.233 us; speedup vs baseline: 1.0234x; 1.0234x over previous
//
#include <hip/hip_runtime.h>
#include <hip/hip_bf16.h>
#include <math.h>

typedef __bf16 bf16;
typedef __bf16 bf16x8 __attribute__((ext_vector_type(8)));
typedef __bf16 bf16x4 __attribute__((ext_vector_type(4)));
typedef float f32x4 __attribute__((ext_vector_type(4)));
typedef float f32x16 __attribute__((ext_vector_type(16)));

#define MFMA16(a, b, c) __builtin_amdgcn_mfma_f32_16x16x32_bf16((a), (b), (c), 0, 0, 0)
#define MFMA32(a, b, c) __builtin_amdgcn_mfma_f32_32x32x16_bf16((a), (b), (c), 0, 0, 0)

#define N_NODES 4096
#define C_DIM   256
#define E_EDGES 131072
#define APAD    280   // LDS A-row stride (elements): 560B, 16B-aligned
#define TPAD    264   // Trow stride (floats)

// ---------------------------------------------------------------------------
// dtype helpers: inputs may be fp32 (per reference) or bf16 (per dataset).
// ---------------------------------------------------------------------------
__device__ __forceinline__ float ldf(const void* p, int i, bool f32) {
    return f32 ? ((const float*)p)[i] : (float)((const bf16*)p)[i];
}

__device__ __forceinline__ bf16x8 ld8(const void* base, size_t off, bool f32) {
    if (f32) {
        const float* p = (const float*)base + off;
        float4 a = *(const float4*)p;
        float4 b = *(const float4*)(p + 4);
        bf16x8 r;
        r[0] = (bf16)a.x; r[1] = (bf16)a.y; r[2] = (bf16)a.z; r[3] = (bf16)a.w;
        r[4] = (bf16)b.x; r[5] = (bf16)b.y; r[6] = (bf16)b.z; r[7] = (bf16)b.w;
        return r;
    }
    return *(const bf16x8*)((const bf16*)base + off);
}

// packed f32->bf16 pair (no builtin on gfx950; RNE)
__device__ __forceinline__ unsigned cvtpk(float a, float b) {
    unsigned r;
    asm("v_cvt_pk_bf16_f32 %0, %1, %2" : "=v"(r) : "v"(a), "v"(b));
    return r;
}
// swap hi-32-lanes of a with lo-32-lanes of b (both modified)
__device__ __forceinline__ void pl32swap(unsigned &a, unsigned &b) {
    asm volatile("v_permlane32_swap_b32 %0, %1" : "+v"(a), "+v"(b));
}

union PW { unsigned u[4]; bf16x8 v; };

__global__ __launch_bounds__(64) void detect_dtype(const void* x, int* flag)
{
    const bf16* xb = (const bf16*)x;
    int tid = threadIdx.x;
    int bad = 0;
    for (int i = tid; i < 4096; i += 64) {
        float v = fabsf((float)xb[i]);
        if (!(v >= 1e-6f && v <= 100.0f)) bad++;
    }
#pragma unroll
    for (int m = 1; m < 64; m <<= 1) bad += __shfl_xor(bad, m);
    if (tid == 0) *flag = (bad > 400) ? 1 : 0;
}

__global__ __launch_bounds__(256) void convert_inputs(
    const void* s0, const void* s1, const void* s2, const void* s3, const void* s4,
    bf16* dst, const int* flag)
{
    int idx = blockIdx.x * 256 + threadIdx.x;  // 6400 blocks -> 1638400
    const void* src; int local;
    if (idx < 1048576)      { src = s0; local = idx; }
    else if (idx < 1245184) { src = s1; local = idx - 1048576; }
    else if (idx < 1310720) { src = s2; local = idx - 1245184; }
    else if (idx < 1507328) { src = s3; local = idx - 1310720; }
    else                    { src = s4; local = idx - 1507328; }
    if (*flag) dst[idx] = (bf16)(((const float*)src)[local]);
    else ((unsigned short*)dst)[idx] = ((const unsigned short*)src)[local];
}

// ---------------------------------------------------------------------------
// CSR build
// ---------------------------------------------------------------------------
__global__ __launch_bounds__(256) void edge_hist(
    const int* __restrict__ ecol, int* __restrict__ counts)
{
    int e = blockIdx.x * 256 + threadIdx.x;
    atomicAdd(&counts[ecol[e]], 1);
}

__global__ __launch_bounds__(256) void edge_scan(
    const int* __restrict__ counts, int* __restrict__ offsets,
    int* __restrict__ cursor)
{
    __shared__ int part[256];
    __shared__ int pref[257];
    int t = threadIdx.x;
    int base = t * 16;
    int s = 0;
#pragma unroll
    for (int i = 0; i < 16; ++i) s += counts[base + i];
    part[t] = s;
    __syncthreads();
    if (t == 0) {
        int run = 0;
        for (int i = 0; i < 256; ++i) { pref[i] = run; run += part[i]; }
        pref[256] = run;
    }
    __syncthreads();
    int off = pref[t];
#pragma unroll
    for (int i = 0; i < 16; ++i) {
        offsets[base + i] = off;
        cursor[base + i]  = off;
        off += counts[base + i];
    }
    if (t == 255) offsets[4096] = off;
}

__global__ __launch_bounds__(256) void edge_scatter(
    const int* __restrict__ ecol, int* __restrict__ cursor,
    int* __restrict__ eid)
{
    int e = blockIdx.x * 256 + threadIdx.x;
    int pos = atomicAdd(&cursor[ecol[e]], 1);
    eid[pos] = e;
}

// ---------------------------------------------------------------------------
// Generic GEMM: C[m][n] = sum_k A[m][k] * W[n][k] + bias[n] (+ resid)
// ---------------------------------------------------------------------------
__global__ __launch_bounds__(256) void gemm_bt(
    const bf16* __restrict__ A, int lda,
    const bf16* __restrict__ W, int ldw,
    const void* __restrict__ bias,
    void* __restrict__ Cout, int ldc, int c_f32,
    const bf16* __restrict__ resid, int ldr,
    int K, const int* __restrict__ flag)
{
    const bool f32 = (*flag != 0);
    const int wave = threadIdx.x >> 6;
    const int lane = threadIdx.x & 63;
    const int quad = lane >> 4;
    const int l16  = lane & 15;
    const int m_base = blockIdx.x * 32;
    const int n_base = blockIdx.y * 256 + wave * 64;

    const bf16* a0p = A + (size_t)(m_base + l16) * lda + quad * 8;
    const bf16* a1p = a0p + (size_t)16 * lda;
    const bf16* wp  = W + (size_t)(n_base + l16) * ldw + quad * 8;

    f32x4 acc[2][4] = {};
    for (int k = 0; k < K; k += 32) {
        bf16x8 a0 = *(const bf16x8*)(a0p + k);
        bf16x8 a1 = *(const bf16x8*)(a1p + k);
#pragma unroll
        for (int nt = 0; nt < 4; ++nt) {
            bf16x8 b = *(const bf16x8*)(wp + (size_t)nt * 16 * ldw + k);
            acc[0][nt] = MFMA16(a0, b, acc[0][nt]);
            acc[1][nt] = MFMA16(a1, b, acc[1][nt]);
        }
    }
#pragma unroll
    for (int mt = 0; mt < 2; ++mt) {
#pragma unroll
        for (int nt = 0; nt < 4; ++nt) {
            int col = n_base + nt * 16 + l16;
            float bv = bias ? ldf(bias, col, f32) : 0.0f;
#pragma unroll
            for (int r = 0; r < 4; ++r) {
                int row = m_base + mt * 16 + quad * 4 + r;
                float v = acc[mt][nt][r] + bv;
                if (resid) v += (float)resid[(size_t)row * ldr + col];
                if (c_f32) ((float*)Cout)[(size_t)row * ldc + col] = v;
                else       ((bf16*)Cout)[(size_t)row * ldc + col] = (bf16)v;
            }
        }
    }
}

// ---------------------------------------------------------------------------
// U/V precompute in ONE launch: grid (128, 2). y=0: U = x @ ew[:, 0:256]^T;
// y=1: V = x @ ew[:, 256:512]^T.
// ---------------------------------------------------------------------------
__global__ __launch_bounds__(256) void gemm_uv(
    const bf16* __restrict__ x, const bf16* __restrict__ ew,
    bf16* __restrict__ U, bf16* __restrict__ V)
{
    const int wave = threadIdx.x >> 6;
    const int lane = threadIdx.x & 63;
    const int quad = lane >> 4;
    const int l16  = lane & 15;
    const int m_base = blockIdx.x * 32;
    bf16* dst = blockIdx.y ? V : U;
    const bf16* W = ew + blockIdx.y * 256;

    const bf16* a0p = x + (size_t)(m_base + l16) * 256 + quad * 8;
    const bf16* a1p = a0p + (size_t)16 * 256;
    const bf16* wp  = W + (size_t)(wave * 64 + l16) * 768 + quad * 8;

    f32x4 acc[2][4] = {};
#pragma unroll
    for (int kk = 0; kk < 8; ++kk) {
        int k = kk * 32;
        bf16x8 a0 = *(const bf16x8*)(a0p + k);
        bf16x8 a1 = *(const bf16x8*)(a1p + k);
#pragma unroll
        for (int nt = 0; nt < 4; ++nt) {
            bf16x8 b = *(const bf16x8*)(wp + (size_t)nt * 16 * 768 + k);
            acc[0][nt] = MFMA16(a0, b, acc[0][nt]);
            acc[1][nt] = MFMA16(a1, b, acc[1][nt]);
        }
    }
#pragma unroll
    for (int mt = 0; mt < 2; ++mt)
#pragma unroll
        for (int nt = 0; nt < 4; ++nt) {
            int col = wave * 64 + nt * 16 + l16;
#pragma unroll
            for (int r = 0; r < 4; ++r) {
                int row = m_base + mt * 16 + quad * 4 + r;
                dst[(size_t)row * 256 + col] = (bf16)acc[mt][nt][r];
            }
        }
}

// ---------------------------------------------------------------------------
// Plain V transpose: vt[c][n] = V[n][c]  (V = qkv cols 512..768)
// ---------------------------------------------------------------------------
__global__ __launch_bounds__(256) void transpose_v(
    const bf16* __restrict__ qkv, bf16* __restrict__ vt)
{
    __shared__ bf16 t[32][65];
    const int n0 = blockIdx.x * 64;
    const int c0 = blockIdx.y * 32;
    const int tid = threadIdx.x;
    {
        int cl = tid & 31, nl = tid >> 5;
#pragma unroll
        for (int p = 0; p < 8; ++p) {
            int n = nl + p * 8;
            t[cl][n] = qkv[(size_t)(n0 + n) * 768 + 512 + c0 + cl];
        }
    }
    __syncthreads();
    {
        int nn = tid & 63, cc = tid >> 6;
#pragma unroll
        for (int p = 0; p < 8; ++p) {
            int c = cc + p * 4;
            vt[(size_t)(c0 + c) * 4096 + n0 + nn] = t[c][nn];
        }
    }
}

// ---------------------------------------------------------------------------
// Flash attention v3: 32x32 swapped-operand MFMA (unchanged - works).
// ---------------------------------------------------------------------------
__global__ __launch_bounds__(256) void attn_kernel(
    const bf16* __restrict__ qkv,
    const bf16* __restrict__ vt,
    bf16* __restrict__ ctx)
{
    __shared__ float oL[4][32][33];
    __shared__ float mS[4][32];
    __shared__ float lS[4][32];
    const int tid  = threadIdx.x;
    const int wave = tid >> 6;
    const int lane = tid & 63;
    const int l32  = lane & 31;
    const int hl   = lane >> 5;
    const int h  = blockIdx.x >> 7;
    const int qt = blockIdx.x & 127;

    const float csc = 1.4426950408889634f * 0.17677669529663687f;

    const bf16* qrow = qkv + (size_t)(qt * 32 + l32) * 768 + h * 32 + hl * 8;
    bf16x8 qf1 = *(const bf16x8*)qrow;
    bf16x8 qf2 = *(const bf16x8*)(qrow + 16);

    const bf16* kbp = qkv + 256 + h * 32 + hl * 8;
    const bf16* vrp = vt + (size_t)(h * 32 + l32) * 4096 + hl * 8;

    float mrun = -INFINITY, msc = -INFINITY, lacc = 0.f;
    f32x16 oacc = {};
    const f32x16 z16 = {};

    const int kbeg = wave * 1024;
    for (int k0 = kbeg; k0 < kbeg + 1024; k0 += 32) {
        const bf16* kp = kbp + (size_t)(k0 + l32) * 768;
        bf16x8 kf1 = *(const bf16x8*)kp;
        bf16x8 kf2 = *(const bf16x8*)(kp + 16);
        bf16x8 vf1 = *(const bf16x8*)(vrp + k0);
        bf16x8 vf2 = *(const bf16x8*)(vrp + k0 + 16);

        f32x16 s = MFMA32(kf1, qf1, z16);
        s = MFMA32(kf2, qf2, s);

        float a0 = fmaxf(fmaxf(s[0], s[1]), fmaxf(s[2], s[3]));
        float a1 = fmaxf(fmaxf(s[4], s[5]), fmaxf(s[6], s[7]));
        float a2 = fmaxf(fmaxf(s[8], s[9]), fmaxf(s[10], s[11]));
        float a3 = fmaxf(fmaxf(s[12], s[13]), fmaxf(s[14], s[15]));
        float tm = fmaxf(fmaxf(a0, a1), fmaxf(a2, a3));
        tm = fmaxf(tm, __shfl_xor(tm, 32));

        if (__any(tm > mrun)) {
            float nm = fmaxf(mrun, tm);
            float nmsc = nm * csc;
            float al = exp2f(msc - nmsc);
            mrun = nm; msc = nmsc;
            lacc *= al;
#pragma unroll
            for (int i = 0; i < 16; ++i) oacc[i] *= al;
        }

        float p[16];
#pragma unroll
        for (int i = 0; i < 16; ++i) {
            p[i] = exp2f(__builtin_fmaf(s[i], csc, -msc));
            lacc += p[i];
        }

        unsigned w0 = cvtpk(p[0], p[1]),  w1 = cvtpk(p[2], p[3]);
        unsigned w2 = cvtpk(p[4], p[5]),  w3 = cvtpk(p[6], p[7]);
        unsigned w4 = cvtpk(p[8], p[9]),  w5 = cvtpk(p[10], p[11]);
        unsigned w6 = cvtpk(p[12], p[13]), w7 = cvtpk(p[14], p[15]);
        pl32swap(w0, w2); pl32swap(w1, w3);
        pl32swap(w4, w6); pl32swap(w5, w7);
        PW f1; f1.u[0] = w0; f1.u[1] = w1; f1.u[2] = w2; f1.u[3] = w3;
        PW f2; f2.u[0] = w4; f2.u[1] = w5; f2.u[2] = w6; f2.u[3] = w7;

        oacc = MFMA32(vf1, f1.v, oacc);
        oacc = MFMA32(vf2, f2.v, oacc);
    }

    lacc += __shfl_xor(lacc, 32);
    if (hl == 0) { mS[wave][l32] = mrun; lS[wave][l32] = lacc; }
#pragma unroll
    for (int i = 0; i < 16; ++i) {
        int d = (i & 3) + 8 * (i >> 2) + 4 * hl;
        oL[wave][l32][d] = oacc[i];
    }
    __syncthreads();
    {
        int q = tid >> 3, d0 = (tid & 7) * 4;
        float m0 = mS[0][q], m1 = mS[1][q], m2 = mS[2][q], m3 = mS[3][q];
        float ms = fmaxf(fmaxf(m0, m1), fmaxf(m2, m3));
        float f0 = exp2f((m0 - ms) * csc), f1 = exp2f((m1 - ms) * csc);
        float f2 = exp2f((m2 - ms) * csc), f3 = exp2f((m3 - ms) * csc);
        float ls = lS[0][q] * f0 + lS[1][q] * f1 + lS[2][q] * f2 + lS[3][q] * f3;
        float inv = 1.0f / ls;
        bf16x4 o4;
#pragma unroll
        for (int i = 0; i < 4; ++i) {
            int d = d0 + i;
            float v = (oL[0][q][d] * f0 + oL[1][q][d] * f1 +
                       oL[2][q][d] * f2 + oL[3][q][d] * f3) * inv;
            o4[i] = (bf16)v;
        }
        *(bf16x4*)(ctx + (size_t)(qt * 32 + q) * 256 + h * 32 + d0) = o4;
    }
}

// ---------------------------------------------------------------------------
// Edge GEMM v6: R7 structure with SEQUENTIAL output. Stores msgpre[e] in
// natural edge order -> pure streaming write (no epos indirection, no
// random-granule scatter). node_ln gathers via eid instead (random 512B
// READS, absorbed by the 256MB L3 since msgpre was just written). Tests the
// last untested axis after R4/R6/R7/R8 all converged at ~94us: the scattered
// CSR-slot write pattern.
// ---------------------------------------------------------------------------
__global__ __launch_bounds__(256, 4) void edge_gemm(
    const void* __restrict__ eattr,
    const bf16* __restrict__ ew,          // [256][768]; cols 512.. used
    const void* __restrict__ eb,
    bf16* __restrict__ msgpre, const int* __restrict__ flag)
{
    __shared__ char smem[64 * APAD * 2];          // 35840 B (Asm / Trow overlay)
    bf16* Asm = (bf16*)smem;                      // [64][APAD]
    float (*Trow)[TPAD] = (float(*)[TPAD])smem;   // epilogue reuse: 32 x 264 f32

    const bool f32 = (*flag != 0);
    const int tid  = threadIdx.x;
    const int wave = tid >> 6;
    const int lane = tid & 63;
    const int quad = lane >> 4;
    const int l16  = lane & 15;
    const int e_base = blockIdx.x * 64;

    const bf16* wp = ew + (size_t)(wave * 64 + l16) * 768 + 512 + quad * 8;

    // ---- A: 64 eattr rows -> padded LDS, coalesced (128B/thread) ----
    {
        int row   = tid >> 2;
        int cbase = (tid & 3) * 64;
        bf16* dst = Asm + row * APAD + cbase;
        if (!f32) {
            const bf16* src = (const bf16*)eattr + (size_t)(e_base + row) * 256 + cbase;
#pragma unroll
            for (int j = 0; j < 8; ++j)
                *(bf16x8*)(dst + j * 8) = *(const bf16x8*)(src + j * 8);
        } else {
            const float* src = (const float*)eattr + (size_t)(e_base + row) * 256 + cbase;
#pragma unroll
            for (int j = 0; j < 8; ++j) {
                float4 a = *(const float4*)(src + j * 8);
                float4 b = *(const float4*)(src + j * 8 + 4);
                bf16x8 r;
                r[0] = (bf16)a.x; r[1] = (bf16)a.y; r[2] = (bf16)a.z; r[3] = (bf16)a.w;
                r[4] = (bf16)b.x; r[5] = (bf16)b.y; r[6] = (bf16)b.z; r[7] = (bf16)b.w;
                *(bf16x8*)(dst + j * 8) = r;
            }
        }
    }
    __syncthreads();

    // ---- K loop: B per-k0 from L2, A from LDS, no barriers ----
    f32x4 acc[4][4] = {};
#pragma unroll
    for (int k0 = 0; k0 < 8; ++k0) {
        bf16x8 b[4];
#pragma unroll
        for (int nt = 0; nt < 4; ++nt)
            b[nt] = *(const bf16x8*)(wp + (size_t)nt * 16 * 768 + k0 * 32);
#pragma unroll
        for (int mt = 0; mt < 4; ++mt) {
            bf16x8 af = *(const bf16x8*)(Asm + (mt * 16 + l16) * APAD + k0 * 32 + quad * 8);
#pragma unroll
            for (int nt = 0; nt < 4; ++nt)
                acc[mt][nt] = MFMA16(af, b[nt], acc[mt][nt]);
        }
    }

    // ---- epilogue: +eb -> swizzled Trow -> SEQUENTIAL coalesced stores ----
    float ebv[4];
#pragma unroll
    for (int nt = 0; nt < 4; ++nt)
        ebv[nt] = ldf(eb, wave * 64 + nt * 16 + l16, f32);

    for (int p = 0; p < 2; ++p) {
        __syncthreads();   // A-reads done (p=0) / Trow WAR (p=1)
#pragma unroll
        for (int mtl = 0; mtl < 2; ++mtl) {
            int mt = p * 2 + mtl;
#pragma unroll
            for (int nt = 0; nt < 4; ++nt) {
                int c = wave * 64 + nt * 16 + l16;
                int cs = c ^ (((c >> 5) & 7) << 2);     // self-XOR swizzle
#pragma unroll
                for (int r = 0; r < 4; ++r)
                    Trow[mtl * 16 + quad * 4 + r][cs] = acc[mt][nt][r] + ebv[nt];
            }
        }
        __syncthreads();
        {
            int row = tid >> 3;          // 0..31
            int seg = tid & 7;           // 32-col segment
            int e = e_base + p * 32 + row;         // natural edge order
            const float* tr = Trow[row];
            const int t4 = (seg & 7) << 2;
            bf16* op = msgpre + (size_t)e * 256 + seg * 32;
#pragma unroll
            for (int i = 0; i < 4; ++i) {
                float4 a = *(const float4*)(tr + ((seg * 32 + i * 8) ^ t4));
                float4 b = *(const float4*)(tr + ((seg * 32 + i * 8 + 4) ^ t4));
                bf16x8 o;
                o[0] = (bf16)a.x; o[1] = (bf16)a.y; o[2] = (bf16)a.z; o[3] = (bf16)a.w;
                o[4] = (bf16)b.x; o[5] = (bf16)b.y; o[6] = (bf16)b.z; o[7] = (bf16)b.w;
                *(bf16x8*)(op + i * 8) = o;
            }
        }
    }
}

// ---------------------------------------------------------------------------
// Stage 2: per-node LN+ReLU+sum. Block = node; gathers msgpre[eid[pos]]
// (random 512B reads, L3-absorbed) + U[erow] (L2-hot) + V[node].
// ---------------------------------------------------------------------------
__global__ __launch_bounds__(256) void node_ln(
    const bf16* __restrict__ msgpre,
    const int* __restrict__ offsets, const int* __restrict__ eid,
    const int* __restrict__ erow,
    const bf16* __restrict__ U, const bf16* __restrict__ V,
    const void* __restrict__ g1, const void* __restrict__ b1,
    bf16* __restrict__ combined, const int* __restrict__ flag)
{
    __shared__ float accL[4][256];
    const bool f32 = (*flag != 0);
    const int wave = threadIdx.x >> 6;
    const int lane = threadIdx.x & 63;
    const int node = blockIdx.x;
    const int start = offsets[node];
    const int cnt   = offsets[node + 1] - start;

    float glv[4], blv[4], vv[4];
#pragma unroll
    for (int i = 0; i < 4; ++i) {
        glv[i] = ldf(g1, lane * 4 + i, f32);
        blv[i] = ldf(b1, lane * 4 + i, f32);
    }
    {
        bf16x4 v4 = *(const bf16x4*)(V + (size_t)node * 256 + lane * 4);
#pragma unroll
        for (int i = 0; i < 4; ++i) vv[i] = (float)v4[i];
    }

    float nacc[4] = {0.f, 0.f, 0.f, 0.f};
    for (int i = wave; i < cnt; i += 4) {
        int pos = start + i;
        int e  = eid[pos];                              // wave-uniform scalar
        int er = erow[e];                               // wave-uniform scalar
        bf16x4 t4 = *(const bf16x4*)(msgpre + (size_t)e * 256 + lane * 4);
        bf16x4 u4 = *(const bf16x4*)(U + (size_t)er * 256 + lane * 4);
        float val[4];
        float s = 0.f, q = 0.f;
#pragma unroll
        for (int j = 0; j < 4; ++j) {
            val[j] = (float)t4[j] + (float)u4[j] + vv[j];
            s += val[j];
            q = __builtin_fmaf(val[j], val[j], q);
        }
#pragma unroll
        for (int msk = 1; msk < 64; msk <<= 1) {
            s += __shfl_xor(s, msk);
            q += __shfl_xor(q, msk);
        }
        float mean = s * (1.0f / 256.0f);
        float var  = q * (1.0f / 256.0f) - mean * mean;
        float rstd = rsqrtf(var + 1e-5f);
#pragma unroll
        for (int j = 0; j < 4; ++j)
            nacc[j] += fmaxf((val[j] - mean) * rstd * glv[j] + blv[j], 0.0f);
    }
#pragma unroll
    for (int j = 0; j < 4; ++j) accL[wave][lane * 4 + j] = nacc[j];
    __syncthreads();
    if (wave == 0) {
        bf16x4 o4;
#pragma unroll
        for (int j = 0; j < 4; ++j) {
            int c = lane * 4 + j;
            float s = (accL[0][c] + accL[1][c]) + (accL[2][c] + accL[3][c]);
            o4[j] = (bf16)s;
        }
        *(bf16x4*)(combined + (size_t)node * 512 + 256 + lane * 4) = o4;
    }
}

// ---------------------------------------------------------------------------
// Fallback (round-3 path) if ws too small for msgpre buffer.
// ---------------------------------------------------------------------------
__global__ __launch_bounds__(256) void edge_node(
    const bf16* __restrict__ x,
    const int* __restrict__ erow,
    const void* __restrict__ eattr,
    const bf16* __restrict__ ew,
    const void* __restrict__ eb,
    const void* __restrict__ g1, const void* __restrict__ b1,
    const int* __restrict__ offsets, const int* __restrict__ eid,
    bf16* __restrict__ combined, const int* __restrict__ flag)
{
    __shared__ float part[32][4][2];
    const bool f32 = (*flag != 0);
    const int wave = threadIdx.x >> 6;
    const int lane = threadIdx.x & 63;
    const int quad = lane >> 4;
    const int l16  = lane & 15;
    const int n = blockIdx.x;
    const int start = offsets[n];
    const int cnt   = offsets[n + 1] - start;

    float gv[4], bv[4], ebv[4];
#pragma unroll
    for (int nt = 0; nt < 4; ++nt) {
        int col = wave * 64 + nt * 16 + l16;
        gv[nt]  = ldf(g1, col, f32);
        bv[nt]  = ldf(b1, col, f32);
        ebv[nt] = ldf(eb, col, f32);
    }
    const bf16* wp = ew + (size_t)(wave * 64 + l16) * 768 + quad * 8;
    const bf16* xn = x + (size_t)n * 256 + quad * 8;

    f32x4 acc1[4] = {};
#pragma unroll
    for (int kk = 0; kk < 8; ++kk) {
        bf16x8 a = *(const bf16x8*)(xn + kk * 32);
#pragma unroll
        for (int nt = 0; nt < 4; ++nt) {
            bf16x8 b = *(const bf16x8*)(wp + (size_t)nt * 16 * 768 + 256 + kk * 32);
            acc1[nt] = MFMA16(a, b, acc1[nt]);
        }
    }
    float nacc[4] = {0.f, 0.f, 0.f, 0.f};
    for (int c0 = 0; c0 < cnt; c0 += 32) {
        int i0 = c0 + l16;      i0 = (i0 < cnt) ? i0 : 0;
        int i1 = c0 + 16 + l16; i1 = (i1 < cnt) ? i1 : 0;
        int e0 = eid[start + i0];
        int e1 = eid[start + i1];
        const bf16* xr0 = x + (size_t)erow[e0] * 256 + quad * 8;
        const bf16* xr1 = x + (size_t)erow[e1] * 256 + quad * 8;
        f32x4 acc[2][4];
#pragma unroll
        for (int nt = 0; nt < 4; ++nt) { acc[0][nt] = acc1[nt]; acc[1][nt] = acc1[nt]; }
#pragma unroll
        for (int kk = 0; kk < 8; ++kk) {
            bf16x8 a0 = *(const bf16x8*)(xr0 + kk * 32);
            bf16x8 a1 = *(const bf16x8*)(xr1 + kk * 32);
#pragma unroll
            for (int nt = 0; nt < 4; ++nt) {
                bf16x8 b = *(const bf16x8*)(wp + (size_t)nt * 16 * 768 + kk * 32);
                acc[0][nt] = MFMA16(a0, b, acc[0][nt]);
                acc[1][nt] = MFMA16(a1, b, acc[1][nt]);
            }
        }
#pragma unroll
        for (int kk = 0; kk < 8; ++kk) {
            int koff = quad * 8 + kk * 32;
            bf16x8 a0 = ld8(eattr, (size_t)e0 * 256 + koff, f32);
            bf16x8 a1 = ld8(eattr, (size_t)e1 * 256 + koff, f32);
#pragma unroll
            for (int nt = 0; nt < 4; ++nt) {
                bf16x8 b = *(const bf16x8*)(wp + (size_t)nt * 16 * 768 + 512 + kk * 32);
                acc[0][nt] = MFMA16(a0, b, acc[0][nt]);
                acc[1][nt] = MFMA16(a1, b, acc[1][nt]);
            }
        }
#pragma unroll
        for (int mt = 0; mt < 2; ++mt)
#pragma unroll
            for (int nt = 0; nt < 4; ++nt)
#pragma unroll
                for (int r = 0; r < 4; ++r) acc[mt][nt][r] += ebv[nt];
        float ps[2][4], pq[2][4];
#pragma unroll
        for (int mt = 0; mt < 2; ++mt)
#pragma unroll
            for (int r = 0; r < 4; ++r) {
                float s = 0.f, q = 0.f;
#pragma unroll
                for (int nt = 0; nt < 4; ++nt) {
                    float v = acc[mt][nt][r];
                    s += v; q += v * v;
                }
                ps[mt][r] = s; pq[mt][r] = q;
            }
#pragma unroll
        for (int msk = 1; msk < 16; msk <<= 1)
#pragma unroll
            for (int mt = 0; mt < 2; ++mt)
#pragma unroll
                for (int r = 0; r < 4; ++r) {
                    ps[mt][r] += __shfl_xor(ps[mt][r], msk);
                    pq[mt][r] += __shfl_xor(pq[mt][r], msk);
                }
        if (l16 == 0) {
#pragma unroll
            for (int mt = 0; mt < 2; ++mt)
#pragma unroll
                for (int r = 0; r < 4; ++r) {
                    part[mt * 16 + quad * 4 + r][wave][0] = ps[mt][r];
                    part[mt * 16 + quad * 4 + r][wave][1] = pq[mt][r];
                }
        }
        __syncthreads();
#pragma unroll
        for (int mt = 0; mt < 2; ++mt)
#pragma unroll
            for (int r = 0; r < 4; ++r) {
                int row = mt * 16 + quad * 4 + r;
                float s = part[row][0][0] + part[row][1][0] + part[row][2][0] + part[row][3][0];
                float q = part[row][0][1] + part[row][1][1] + part[row][2][1] + part[row][3][1];
                float mean = s * (1.0f / 256.0f);
                float var  = q * (1.0f / 256.0f) - mean * mean;
                float rstd = rsqrtf(var + 1e-5f);
                if ((c0 + row) < cnt) {
#pragma unroll
                    for (int nt = 0; nt < 4; ++nt) {
                        float val = (acc[mt][nt][r] - mean) * rstd * gv[nt] + bv[nt];
                        nacc[nt] += fmaxf(val, 0.0f);
                    }
                }
            }
        __syncthreads();
    }
#pragma unroll
    for (int nt = 0; nt < 4; ++nt) {
        nacc[nt] += __shfl_xor(nacc[nt], 16);
        nacc[nt] += __shfl_xor(nacc[nt], 32);
    }
    if (quad == 0) {
#pragma unroll
        for (int nt = 0; nt < 4; ++nt)
            combined[(size_t)n * 512 + 256 + wave * 64 + nt * 16 + l16] = (bf16)nacc[nt];
    }
}

// ---------------------------------------------------------------------------
// Fused output projection + bias + residual + LayerNorm2. M=16 rows/block
// (grid 256 = full GPU), K=512.
// ---------------------------------------------------------------------------
__global__ __launch_bounds__(256) void gemm_ln(
    const bf16* __restrict__ A,          // combined [4096][512]
    const bf16* __restrict__ W,          // ow [256][512]
    const void* __restrict__ bias,       // o_b
    const bf16* __restrict__ resid,      // x_bf [4096][256]
    const void* __restrict__ g, const void* __restrict__ bb,
    void* __restrict__ out, const int* __restrict__ flag)
{
    __shared__ float stats[16][4][2];
    const bool f32 = (*flag != 0);
    const int wave = threadIdx.x >> 6;
    const int lane = threadIdx.x & 63;
    const int quad = lane >> 4;
    const int l16  = lane & 15;
    const int m_base = blockIdx.x * 16;

    const bf16* ap = A + (size_t)(m_base + l16) * 512 + quad * 8;
    const bf16* wp = W + (size_t)(wave * 64 + l16) * 512 + quad * 8;

    f32x4 acc[4] = {};
#pragma unroll
    for (int kk = 0; kk < 16; ++kk) {
        int k = kk * 32;
        bf16x8 a = *(const bf16x8*)(ap + k);
#pragma unroll
        for (int nt = 0; nt < 4; ++nt) {
            bf16x8 b = *(const bf16x8*)(wp + (size_t)nt * 16 * 512 + k);
            acc[nt] = MFMA16(a, b, acc[nt]);
        }
    }
    float s[4] = {}, q[4] = {};
#pragma unroll
    for (int nt = 0; nt < 4; ++nt) {
        int col = wave * 64 + nt * 16 + l16;
        float bv = ldf(bias, col, f32);
#pragma unroll
        for (int r = 0; r < 4; ++r) {
            int row = m_base + quad * 4 + r;
            float v = acc[nt][r] + bv + (float)resid[(size_t)row * 256 + col];
            acc[nt][r] = v;
            s[r] += v;
            q[r] = __builtin_fmaf(v, v, q[r]);
        }
    }
#pragma unroll
    for (int msk = 1; msk < 16; msk <<= 1)
#pragma unroll
        for (int r = 0; r < 4; ++r) {
            s[r] += __shfl_xor(s[r], msk);
            q[r] += __shfl_xor(q[r], msk);
        }
    if (l16 == 0) {
#pragma unroll
        for (int r = 0; r < 4; ++r) {
            stats[quad * 4 + r][wave][0] = s[r];
            stats[quad * 4 + r][wave][1] = q[r];
        }
    }
    __syncthreads();
#pragma unroll
    for (int r = 0; r < 4; ++r) {
        int row16 = quad * 4 + r;
        float ss = (stats[row16][0][0] + stats[row16][1][0]) +
                   (stats[row16][2][0] + stats[row16][3][0]);
        float qq = (stats[row16][0][1] + stats[row16][1][1]) +
                   (stats[row16][2][1] + stats[row16][3][1]);
        float mean = ss * (1.0f / 256.0f);
        float var  = qq * (1.0f / 256.0f) - mean * mean;
        float rstd = rsqrtf(var + 1e-5f);
        int row = m_base + row16;
#pragma unroll
        for (int nt = 0; nt < 4; ++nt) {
            int col = wave * 64 + nt * 16 + l16;
            float o = (acc[nt][r] - mean) * rstd * ldf(g, col, f32) + ldf(bb, col, f32);
            if (f32) ((float*)out)[(size_t)row * 256 + col] = o;
            else     ((bf16*)out)[(size_t)row * 256 + col] = (bf16)o;
        }
    }
}

// ---------------------------------------------------------------------------
extern "C" void kernel_launch(void* const* d_in, const int* in_sizes, int n_in,
                              void* d_out, int out_size, void* d_ws, size_t ws_size,
                              hipStream_t stream)
{
    const void* x_raw  = d_in[0];
    const int*  eidx   = (const int*)d_in[1];
    const void* eattr  = d_in[2];
    const void* in_w   = d_in[3];
    const void* in_b   = d_in[4];
    const void* ao_w   = d_in[5];
    const void* ao_b   = d_in[6];
    const void* e_w    = d_in[7];
    const void* e_b    = d_in[8];
    const void* g1     = d_in[9];
    const void* b1     = d_in[10];
    const void* o_w    = d_in[11];
    const void* o_b    = d_in[12];
    const void* g2     = d_in[13];
    const void* b2     = d_in[14];

    char* ws = (char*)d_ws;
    bf16*  qkv      = (bf16*)(ws);               // 6291456 B
    bf16*  vt       = (bf16*)(ws + 6291456);     // 2097152 B
    bf16*  ctx      = (bf16*)(ws + 8388608);     // 2097152 B
    bf16*  combined = (bf16*)(ws + 10485760);    // 4194304 B
    int*   counts   = (int*)(ws + 14680064);     // 16384 B
    int*   offsets  = (int*)(ws + 14696448);     // 16388 B
    int*   cursor   = (int*)(ws + 14712848);     // 16384 B
    int*   eid      = (int*)(ws + 14729232);     // 524288 B
    bf16*  U        = (bf16*)(ws + 18874368);    // 2097152 B
    bf16*  V        = (bf16*)(ws + 20971520);    // 2097152 B
    bf16*  canon    = (bf16*)(ws + 23068672);    // 3276800 B
    int*   flag     = (int*)(ws + 26345472);     // 4 B
    bf16*  msgpre   = (bf16*)(ws + 26345728);    // 67108864 B -> end 93454592

    const size_t WS_NEEDED = 93454592;

    bf16* x_bf   = canon;
    bf16* inw_bf = canon + 1048576;
    bf16* aow_bf = canon + 1245184;
    bf16* ew_bf  = canon + 1310720;
    bf16* ow_bf  = canon + 1507328;

    const int* erow = eidx;
    const int* ecol = eidx + E_EDGES;

    detect_dtype<<<dim3(1), 64, 0, stream>>>(x_raw, flag);
    convert_inputs<<<dim3(6400), 256, 0, stream>>>(x_raw, in_w, ao_w, e_w, o_w,
                                                   canon, flag);
    // CSR build
    hipMemsetAsync(counts, 0, 16384, stream);
    edge_hist<<<dim3(E_EDGES / 256), 256, 0, stream>>>(ecol, counts);
    edge_scan<<<dim3(1), 256, 0, stream>>>(counts, offsets, cursor);
    edge_scatter<<<dim3(E_EDGES / 256), 256, 0, stream>>>(ecol, cursor, eid);

    // node-level precomputes for the edge MLP: U = x@W0^T, V = x@W1^T (1 launch)
    gemm_uv<<<dim3(128, 2), 256, 0, stream>>>(x_bf, ew_bf, U, V);

    // qkv = x @ in_proj_w^T + in_proj_b
    gemm_bt<<<dim3(128, 3), 256, 0, stream>>>(x_bf, 256, inw_bf, 256, in_b,
                                              qkv, 768, 0, nullptr, 0, 256, flag);
    transpose_v<<<dim3(64, 8), 256, 0, stream>>>(qkv, vt);
    attn_kernel<<<dim3(1024), 256, 0, stream>>>(qkv, vt, ctx);
    gemm_bt<<<dim3(128, 1), 256, 0, stream>>>(ctx, 256, aow_bf, 256, ao_b,
                                              combined, 512, 0, nullptr, 0, 256, flag);
    if (ws_size >= WS_NEEDED) {
        // stage 1: streaming GEMM, rows in NATURAL edge order (sequential writes)
        edge_gemm<<<dim3(E_EDGES / 64), 256, 0, stream>>>(eattr, ew_bf, e_b,
                                                          msgpre, flag);
        // stage 2: per-node LN+ReLU+sum, gathering msgpre[eid[pos]]
        node_ln<<<dim3(N_NODES), 256, 0, stream>>>(msgpre, offsets, eid, erow,
                                                   U, V, g1, b1, combined, flag);
    } else {
        edge_node<<<dim3(N_NODES), 256, 0, stream>>>(x_bf, erow, eattr,
                                                     ew_bf, e_b, g1, b1,
                                                     offsets, eid, combined, flag);
    }
    // fused out-proj + residual + LN2 -> d_out
    gemm_ln<<<dim3(256), 256, 0, stream>>>(combined, ow_bf, o_b, x_bf,
                                           g2, b2, d_out, flag);
}

// Round 11
// 450.419 us; speedup vs baseline: 1.0389x; 1.0151x over previous
//
#include <hip/hip_runtime.h>
#include <hip/hip_bf16.h>
#include <math.h>

typedef __bf16 bf16;
typedef __bf16 bf16x8 __attribute__((ext_vector_type(8)));
typedef __bf16 bf16x4 __attribute__((ext_vector_type(4)));
typedef float f32x4 __attribute__((ext_vector_type(4)));
typedef float f32x16 __attribute__((ext_vector_type(16)));

#define MFMA16(a, b, c) __builtin_amdgcn_mfma_f32_16x16x32_bf16((a), (b), (c), 0, 0, 0)
#define MFMA32(a, b, c) __builtin_amdgcn_mfma_f32_32x32x16_bf16((a), (b), (c), 0, 0, 0)

#define N_NODES 4096
#define C_DIM   256
#define E_EDGES 131072
#define TPAD    264   // Trow stride (floats)

// ---------------------------------------------------------------------------
// dtype helpers: inputs may be fp32 (per reference) or bf16 (per dataset).
// ---------------------------------------------------------------------------
__device__ __forceinline__ float ldf(const void* p, int i, bool f32) {
    return f32 ? ((const float*)p)[i] : (float)((const bf16*)p)[i];
}

__device__ __forceinline__ bf16x8 ld8(const void* base, size_t off, bool f32) {
    if (f32) {
        const float* p = (const float*)base + off;
        float4 a = *(const float4*)p;
        float4 b = *(const float4*)(p + 4);
        bf16x8 r;
        r[0] = (bf16)a.x; r[1] = (bf16)a.y; r[2] = (bf16)a.z; r[3] = (bf16)a.w;
        r[4] = (bf16)b.x; r[5] = (bf16)b.y; r[6] = (bf16)b.z; r[7] = (bf16)b.w;
        return r;
    }
    return *(const bf16x8*)((const bf16*)base + off);
}

// packed f32->bf16 pair (no builtin on gfx950; RNE)
__device__ __forceinline__ unsigned cvtpk(float a, float b) {
    unsigned r;
    asm("v_cvt_pk_bf16_f32 %0, %1, %2" : "=v"(r) : "v"(a), "v"(b));
    return r;
}
// swap hi-32-lanes of a with lo-32-lanes of b (both modified)
__device__ __forceinline__ void pl32swap(unsigned &a, unsigned &b) {
    asm volatile("v_permlane32_swap_b32 %0, %1" : "+v"(a), "+v"(b));
}

union PW { unsigned u[4]; bf16x8 v; };

__global__ __launch_bounds__(64) void detect_dtype(const void* x, int* flag)
{
    const bf16* xb = (const bf16*)x;
    int tid = threadIdx.x;
    int bad = 0;
    for (int i = tid; i < 4096; i += 64) {
        float v = fabsf((float)xb[i]);
        if (!(v >= 1e-6f && v <= 100.0f)) bad++;
    }
#pragma unroll
    for (int m = 1; m < 64; m <<= 1) bad += __shfl_xor(bad, m);
    if (tid == 0) *flag = (bad > 400) ? 1 : 0;
}

__global__ __launch_bounds__(256) void convert_inputs(
    const void* s0, const void* s1, const void* s2, const void* s3, const void* s4,
    bf16* dst, const int* flag)
{
    int idx = blockIdx.x * 256 + threadIdx.x;  // 6400 blocks -> 1638400
    const void* src; int local;
    if (idx < 1048576)      { src = s0; local = idx; }
    else if (idx < 1245184) { src = s1; local = idx - 1048576; }
    else if (idx < 1310720) { src = s2; local = idx - 1245184; }
    else if (idx < 1507328) { src = s3; local = idx - 1310720; }
    else                    { src = s4; local = idx - 1507328; }
    if (*flag) dst[idx] = (bf16)(((const float*)src)[local]);
    else ((unsigned short*)dst)[idx] = ((const unsigned short*)src)[local];
}

// ---------------------------------------------------------------------------
// CSR build
// ---------------------------------------------------------------------------
__global__ __launch_bounds__(256) void edge_hist(
    const int* __restrict__ ecol, int* __restrict__ counts)
{
    int e = blockIdx.x * 256 + threadIdx.x;
    atomicAdd(&counts[ecol[e]], 1);
}

__global__ __launch_bounds__(256) void edge_scan(
    const int* __restrict__ counts, int* __restrict__ offsets,
    int* __restrict__ cursor)
{
    __shared__ int part[256];
    __shared__ int pref[257];
    int t = threadIdx.x;
    int base = t * 16;
    int s = 0;
#pragma unroll
    for (int i = 0; i < 16; ++i) s += counts[base + i];
    part[t] = s;
    __syncthreads();
    if (t == 0) {
        int run = 0;
        for (int i = 0; i < 256; ++i) { pref[i] = run; run += part[i]; }
        pref[256] = run;
    }
    __syncthreads();
    int off = pref[t];
#pragma unroll
    for (int i = 0; i < 16; ++i) {
        offsets[base + i] = off;
        cursor[base + i]  = off;
        off += counts[base + i];
    }
    if (t == 255) offsets[4096] = off;
}

__global__ __launch_bounds__(256) void edge_scatter(
    const int* __restrict__ ecol, int* __restrict__ cursor,
    int* __restrict__ eid)
{
    int e = blockIdx.x * 256 + threadIdx.x;
    int pos = atomicAdd(&cursor[ecol[e]], 1);
    eid[pos] = e;
}

// ---------------------------------------------------------------------------
// Generic GEMM: C[m][n] = sum_k A[m][k] * W[n][k] + bias[n] (+ resid)
// ---------------------------------------------------------------------------
__global__ __launch_bounds__(256) void gemm_bt(
    const bf16* __restrict__ A, int lda,
    const bf16* __restrict__ W, int ldw,
    const void* __restrict__ bias,
    void* __restrict__ Cout, int ldc, int c_f32,
    const bf16* __restrict__ resid, int ldr,
    int K, const int* __restrict__ flag)
{
    const bool f32 = (*flag != 0);
    const int wave = threadIdx.x >> 6;
    const int lane = threadIdx.x & 63;
    const int quad = lane >> 4;
    const int l16  = lane & 15;
    const int m_base = blockIdx.x * 32;
    const int n_base = blockIdx.y * 256 + wave * 64;

    const bf16* a0p = A + (size_t)(m_base + l16) * lda + quad * 8;
    const bf16* a1p = a0p + (size_t)16 * lda;
    const bf16* wp  = W + (size_t)(n_base + l16) * ldw + quad * 8;

    f32x4 acc[2][4] = {};
    for (int k = 0; k < K; k += 32) {
        bf16x8 a0 = *(const bf16x8*)(a0p + k);
        bf16x8 a1 = *(const bf16x8*)(a1p + k);
#pragma unroll
        for (int nt = 0; nt < 4; ++nt) {
            bf16x8 b = *(const bf16x8*)(wp + (size_t)nt * 16 * ldw + k);
            acc[0][nt] = MFMA16(a0, b, acc[0][nt]);
            acc[1][nt] = MFMA16(a1, b, acc[1][nt]);
        }
    }
#pragma unroll
    for (int mt = 0; mt < 2; ++mt) {
#pragma unroll
        for (int nt = 0; nt < 4; ++nt) {
            int col = n_base + nt * 16 + l16;
            float bv = bias ? ldf(bias, col, f32) : 0.0f;
#pragma unroll
            for (int r = 0; r < 4; ++r) {
                int row = m_base + mt * 16 + quad * 4 + r;
                float v = acc[mt][nt][r] + bv;
                if (resid) v += (float)resid[(size_t)row * ldr + col];
                if (c_f32) ((float*)Cout)[(size_t)row * ldc + col] = v;
                else       ((bf16*)Cout)[(size_t)row * ldc + col] = (bf16)v;
            }
        }
    }
}

// ---------------------------------------------------------------------------
// U/V precompute in ONE launch: grid (128, 2). y=0: U = x @ ew[:, 0:256]^T;
// y=1: V = x @ ew[:, 256:512]^T.
// ---------------------------------------------------------------------------
__global__ __launch_bounds__(256) void gemm_uv(
    const bf16* __restrict__ x, const bf16* __restrict__ ew,
    bf16* __restrict__ U, bf16* __restrict__ V)
{
    const int wave = threadIdx.x >> 6;
    const int lane = threadIdx.x & 63;
    const int quad = lane >> 4;
    const int l16  = lane & 15;
    const int m_base = blockIdx.x * 32;
    bf16* dst = blockIdx.y ? V : U;
    const bf16* W = ew + blockIdx.y * 256;

    const bf16* a0p = x + (size_t)(m_base + l16) * 256 + quad * 8;
    const bf16* a1p = a0p + (size_t)16 * 256;
    const bf16* wp  = W + (size_t)(wave * 64 + l16) * 768 + quad * 8;

    f32x4 acc[2][4] = {};
#pragma unroll
    for (int kk = 0; kk < 8; ++kk) {
        int k = kk * 32;
        bf16x8 a0 = *(const bf16x8*)(a0p + k);
        bf16x8 a1 = *(const bf16x8*)(a1p + k);
#pragma unroll
        for (int nt = 0; nt < 4; ++nt) {
            bf16x8 b = *(const bf16x8*)(wp + (size_t)nt * 16 * 768 + k);
            acc[0][nt] = MFMA16(a0, b, acc[0][nt]);
            acc[1][nt] = MFMA16(a1, b, acc[1][nt]);
        }
    }
#pragma unroll
    for (int mt = 0; mt < 2; ++mt)
#pragma unroll
        for (int nt = 0; nt < 4; ++nt) {
            int col = wave * 64 + nt * 16 + l16;
#pragma unroll
            for (int r = 0; r < 4; ++r) {
                int row = m_base + mt * 16 + quad * 4 + r;
                dst[(size_t)row * 256 + col] = (bf16)acc[mt][nt][r];
            }
        }
}

// ---------------------------------------------------------------------------
// Plain V transpose: vt[c][n] = V[n][c]  (V = qkv cols 512..768)
// ---------------------------------------------------------------------------
__global__ __launch_bounds__(256) void transpose_v(
    const bf16* __restrict__ qkv, bf16* __restrict__ vt)
{
    __shared__ bf16 t[32][65];
    const int n0 = blockIdx.x * 64;
    const int c0 = blockIdx.y * 32;
    const int tid = threadIdx.x;
    {
        int cl = tid & 31, nl = tid >> 5;
#pragma unroll
        for (int p = 0; p < 8; ++p) {
            int n = nl + p * 8;
            t[cl][n] = qkv[(size_t)(n0 + n) * 768 + 512 + c0 + cl];
        }
    }
    __syncthreads();
    {
        int nn = tid & 63, cc = tid >> 6;
#pragma unroll
        for (int p = 0; p < 8; ++p) {
            int c = cc + p * 4;
            vt[(size_t)(c0 + c) * 4096 + n0 + nn] = t[c][nn];
        }
    }
}

// ---------------------------------------------------------------------------
// Flash attention v3: 32x32 swapped-operand MFMA (unchanged - works).
// ---------------------------------------------------------------------------
__global__ __launch_bounds__(256) void attn_kernel(
    const bf16* __restrict__ qkv,
    const bf16* __restrict__ vt,
    bf16* __restrict__ ctx)
{
    __shared__ float oL[4][32][33];
    __shared__ float mS[4][32];
    __shared__ float lS[4][32];
    const int tid  = threadIdx.x;
    const int wave = tid >> 6;
    const int lane = tid & 63;
    const int l32  = lane & 31;
    const int hl   = lane >> 5;
    const int h  = blockIdx.x >> 7;
    const int qt = blockIdx.x & 127;

    const float csc = 1.4426950408889634f * 0.17677669529663687f;

    const bf16* qrow = qkv + (size_t)(qt * 32 + l32) * 768 + h * 32 + hl * 8;
    bf16x8 qf1 = *(const bf16x8*)qrow;
    bf16x8 qf2 = *(const bf16x8*)(qrow + 16);

    const bf16* kbp = qkv + 256 + h * 32 + hl * 8;
    const bf16* vrp = vt + (size_t)(h * 32 + l32) * 4096 + hl * 8;

    float mrun = -INFINITY, msc = -INFINITY, lacc = 0.f;
    f32x16 oacc = {};
    const f32x16 z16 = {};

    const int kbeg = wave * 1024;
    for (int k0 = kbeg; k0 < kbeg + 1024; k0 += 32) {
        const bf16* kp = kbp + (size_t)(k0 + l32) * 768;
        bf16x8 kf1 = *(const bf16x8*)kp;
        bf16x8 kf2 = *(const bf16x8*)(kp + 16);
        bf16x8 vf1 = *(const bf16x8*)(vrp + k0);
        bf16x8 vf2 = *(const bf16x8*)(vrp + k0 + 16);

        f32x16 s = MFMA32(kf1, qf1, z16);
        s = MFMA32(kf2, qf2, s);

        float a0 = fmaxf(fmaxf(s[0], s[1]), fmaxf(s[2], s[3]));
        float a1 = fmaxf(fmaxf(s[4], s[5]), fmaxf(s[6], s[7]));
        float a2 = fmaxf(fmaxf(s[8], s[9]), fmaxf(s[10], s[11]));
        float a3 = fmaxf(fmaxf(s[12], s[13]), fmaxf(s[14], s[15]));
        float tm = fmaxf(fmaxf(a0, a1), fmaxf(a2, a3));
        tm = fmaxf(tm, __shfl_xor(tm, 32));

        if (__any(tm > mrun)) {
            float nm = fmaxf(mrun, tm);
            float nmsc = nm * csc;
            float al = exp2f(msc - nmsc);
            mrun = nm; msc = nmsc;
            lacc *= al;
#pragma unroll
            for (int i = 0; i < 16; ++i) oacc[i] *= al;
        }

        float p[16];
#pragma unroll
        for (int i = 0; i < 16; ++i) {
            p[i] = exp2f(__builtin_fmaf(s[i], csc, -msc));
            lacc += p[i];
        }

        unsigned w0 = cvtpk(p[0], p[1]),  w1 = cvtpk(p[2], p[3]);
        unsigned w2 = cvtpk(p[4], p[5]),  w3 = cvtpk(p[6], p[7]);
        unsigned w4 = cvtpk(p[8], p[9]),  w5 = cvtpk(p[10], p[11]);
        unsigned w6 = cvtpk(p[12], p[13]), w7 = cvtpk(p[14], p[15]);
        pl32swap(w0, w2); pl32swap(w1, w3);
        pl32swap(w4, w6); pl32swap(w5, w7);
        PW f1; f1.u[0] = w0; f1.u[1] = w1; f1.u[2] = w2; f1.u[3] = w3;
        PW f2; f2.u[0] = w4; f2.u[1] = w5; f2.u[2] = w6; f2.u[3] = w7;

        oacc = MFMA32(vf1, f1.v, oacc);
        oacc = MFMA32(vf2, f2.v, oacc);
    }

    lacc += __shfl_xor(lacc, 32);
    if (hl == 0) { mS[wave][l32] = mrun; lS[wave][l32] = lacc; }
#pragma unroll
    for (int i = 0; i < 16; ++i) {
        int d = (i & 3) + 8 * (i >> 2) + 4 * hl;
        oL[wave][l32][d] = oacc[i];
    }
    __syncthreads();
    {
        int q = tid >> 3, d0 = (tid & 7) * 4;
        float m0 = mS[0][q], m1 = mS[1][q], m2 = mS[2][q], m3 = mS[3][q];
        float ms = fmaxf(fmaxf(m0, m1), fmaxf(m2, m3));
        float f0 = exp2f((m0 - ms) * csc), f1 = exp2f((m1 - ms) * csc);
        float f2 = exp2f((m2 - ms) * csc), f3 = exp2f((m3 - ms) * csc);
        float ls = lS[0][q] * f0 + lS[1][q] * f1 + lS[2][q] * f2 + lS[3][q] * f3;
        float inv = 1.0f / ls;
        bf16x4 o4;
#pragma unroll
        for (int i = 0; i < 4; ++i) {
            int d = d0 + i;
            float v = (oL[0][q][d] * f0 + oL[1][q][d] * f1 +
                       oL[2][q][d] * f2 + oL[3][q][d] * f3) * inv;
            o4[i] = (bf16)v;
        }
        *(bf16x4*)(ctx + (size_t)(qt * 32 + q) * 256 + h * 32 + d0) = o4;
    }
}

// ---------------------------------------------------------------------------
// Edge GEMM v7b: FLAT-COALESCED staging and stores (R10 design, address fix).
//  - A-stage: thread t loads 16B at flat byte j*4096 + t*16 (wave = 1024B
//    contiguous = 8 lines/instr vs 64 before). LDS store at fb^((row&7)<<4);
//    K-loop reads mirror the XOR (axor = (l16&7)<<4) -> 2 lanes/16B slot.
//  - Store phase: thread t writes cols (t&31)*8 of rows j*8+(t>>5); rows
//    contiguous in msgpre (natural order) -> 1024B contiguous per instr.
//    Trow read: float4 at (c0^swz) and ((c0+4)^swz) -- XOR applied to EACH
//    half's address (R10 bug: eL=c0^swz then eL+4 carries into bit 3 when
//    swz bit2=1, reading the wrong 8-group).
// ---------------------------------------------------------------------------
__global__ __launch_bounds__(256, 4) void edge_gemm(
    const void* __restrict__ eattr,
    const bf16* __restrict__ ew,          // [256][768]; cols 512.. used
    const void* __restrict__ eb,
    bf16* __restrict__ msgpre, const int* __restrict__ flag)
{
    __shared__ char smem[35840];                  // Asm (32KB flat) / Trow overlay
    float (*Trow)[TPAD] = (float(*)[TPAD])smem;   // epilogue reuse: 32 x 264 f32

    const bool f32 = (*flag != 0);
    const int tid  = threadIdx.x;
    const int wave = tid >> 6;
    const int lane = tid & 63;
    const int quad = lane >> 4;
    const int l16  = lane & 15;
    const int e_base = blockIdx.x * 64;

    const bf16* wp = ew + (size_t)(wave * 64 + l16) * 768 + 512 + quad * 8;

    // ---- A: 64 eattr rows -> LDS, FLAT coalesced, row-XOR swizzled ----
    {
        if (!f32) {
            const bf16* src = (const bf16*)eattr + (size_t)e_base * 256;
#pragma unroll
            for (int j = 0; j < 8; ++j) {
                int fb = j * 4096 + tid * 16;
                int sb = fb ^ (((fb >> 9) & 7) << 4);
                *(bf16x8*)(smem + sb) = *(const bf16x8*)((const char*)src + fb);
            }
        } else {
            const float* src = (const float*)eattr + (size_t)e_base * 256;
#pragma unroll
            for (int j = 0; j < 8; ++j) {
                int fb = j * 4096 + tid * 16;            // bf16-tile byte
                int el = j * 2048 + tid * 8;             // f32 elem index
                float4 a = *(const float4*)(src + el);
                float4 b = *(const float4*)(src + el + 4);
                bf16x8 r;
                r[0] = (bf16)a.x; r[1] = (bf16)a.y; r[2] = (bf16)a.z; r[3] = (bf16)a.w;
                r[4] = (bf16)b.x; r[5] = (bf16)b.y; r[6] = (bf16)b.z; r[7] = (bf16)b.w;
                int sb = fb ^ (((fb >> 9) & 7) << 4);
                *(bf16x8*)(smem + sb) = r;
            }
        }
    }
    __syncthreads();

    // ---- K loop: B per-k0 from L2, A from swizzled LDS ----
    const int axor = (l16 & 7) << 4;   // lane-constant read XOR
    f32x4 acc[4][4] = {};
#pragma unroll
    for (int k0 = 0; k0 < 8; ++k0) {
        bf16x8 b[4];
#pragma unroll
        for (int nt = 0; nt < 4; ++nt)
            b[nt] = *(const bf16x8*)(wp + (size_t)nt * 16 * 768 + k0 * 32);
#pragma unroll
        for (int mt = 0; mt < 4; ++mt) {
            int fb = (mt * 16 + l16) * 512 + k0 * 64 + quad * 16;
            bf16x8 af = *(const bf16x8*)(smem + (fb ^ axor));
#pragma unroll
            for (int nt = 0; nt < 4; ++nt)
                acc[mt][nt] = MFMA16(af, b[nt], acc[mt][nt]);
        }
    }

    // ---- epilogue: +eb -> swizzled Trow -> FLAT coalesced stores ----
    float ebv[4];
#pragma unroll
    for (int nt = 0; nt < 4; ++nt)
        ebv[nt] = ldf(eb, wave * 64 + nt * 16 + l16, f32);

    for (int p = 0; p < 2; ++p) {
        __syncthreads();   // A-reads done (p=0) / Trow WAR (p=1)
#pragma unroll
        for (int mtl = 0; mtl < 2; ++mtl) {
            int mt = p * 2 + mtl;
#pragma unroll
            for (int nt = 0; nt < 4; ++nt) {
                int c = wave * 64 + nt * 16 + l16;
                int cs = c ^ (((c >> 5) & 7) << 2);     // self-XOR swizzle
#pragma unroll
                for (int r = 0; r < 4; ++r)
                    Trow[mtl * 16 + quad * 4 + r][cs] = acc[mt][nt][r] + ebv[nt];
            }
        }
        __syncthreads();
        {
            int c0  = (tid & 31) * 8;
            int swz = ((c0 >> 5) & 7) << 2;
#pragma unroll
            for (int j = 0; j < 4; ++j) {
                int row = j * 8 + (tid >> 5);
                const float* tr = Trow[row];
                float4 a = *(const float4*)(tr + (c0 ^ swz));
                float4 b = *(const float4*)(tr + ((c0 + 4) ^ swz));
                bf16x8 o;
                o[0] = (bf16)a.x; o[1] = (bf16)a.y; o[2] = (bf16)a.z; o[3] = (bf16)a.w;
                o[4] = (bf16)b.x; o[5] = (bf16)b.y; o[6] = (bf16)b.z; o[7] = (bf16)b.w;
                *(bf16x8*)(msgpre + (size_t)(e_base + p * 32 + row) * 256 + c0) = o;
            }
        }
    }
}

// ---------------------------------------------------------------------------
// Stage 2: per-node LN+ReLU+sum. Block = node; gathers msgpre[eid[pos]]
// (random 512B reads, L2/L3-absorbed) + U[erow] (L2-hot) + V[node].
// ---------------------------------------------------------------------------
__global__ __launch_bounds__(256) void node_ln(
    const bf16* __restrict__ msgpre,
    const int* __restrict__ offsets, const int* __restrict__ eid,
    const int* __restrict__ erow,
    const bf16* __restrict__ U, const bf16* __restrict__ V,
    const void* __restrict__ g1, const void* __restrict__ b1,
    bf16* __restrict__ combined, const int* __restrict__ flag)
{
    __shared__ float accL[4][256];
    const bool f32 = (*flag != 0);
    const int wave = threadIdx.x >> 6;
    const int lane = threadIdx.x & 63;
    const int node = blockIdx.x;
    const int start = offsets[node];
    const int cnt   = offsets[node + 1] - start;

    float glv[4], blv[4], vv[4];
#pragma unroll
    for (int i = 0; i < 4; ++i) {
        glv[i] = ldf(g1, lane * 4 + i, f32);
        blv[i] = ldf(b1, lane * 4 + i, f32);
    }
    {
        bf16x4 v4 = *(const bf16x4*)(V + (size_t)node * 256 + lane * 4);
#pragma unroll
        for (int i = 0; i < 4; ++i) vv[i] = (float)v4[i];
    }

    float nacc[4] = {0.f, 0.f, 0.f, 0.f};
    for (int i = wave; i < cnt; i += 4) {
        int pos = start + i;
        int e  = eid[pos];                              // wave-uniform scalar
        int er = erow[e];                               // wave-uniform scalar
        bf16x4 t4 = *(const bf16x4*)(msgpre + (size_t)e * 256 + lane * 4);
        bf16x4 u4 = *(const bf16x4*)(U + (size_t)er * 256 + lane * 4);
        float val[4];
        float s = 0.f, q = 0.f;
#pragma unroll
        for (int j = 0; j < 4; ++j) {
            val[j] = (float)t4[j] + (float)u4[j] + vv[j];
            s += val[j];
            q = __builtin_fmaf(val[j], val[j], q);
        }
#pragma unroll
        for (int msk = 1; msk < 64; msk <<= 1) {
            s += __shfl_xor(s, msk);
            q += __shfl_xor(q, msk);
        }
        float mean = s * (1.0f / 256.0f);
        float var  = q * (1.0f / 256.0f) - mean * mean;
        float rstd = rsqrtf(var + 1e-5f);
#pragma unroll
        for (int j = 0; j < 4; ++j)
            nacc[j] += fmaxf((val[j] - mean) * rstd * glv[j] + blv[j], 0.0f);
    }
#pragma unroll
    for (int j = 0; j < 4; ++j) accL[wave][lane * 4 + j] = nacc[j];
    __syncthreads();
    if (wave == 0) {
        bf16x4 o4;
#pragma unroll
        for (int j = 0; j < 4; ++j) {
            int c = lane * 4 + j;
            float s = (accL[0][c] + accL[1][c]) + (accL[2][c] + accL[3][c]);
            o4[j] = (bf16)s;
        }
        *(bf16x4*)(combined + (size_t)node * 512 + 256 + lane * 4) = o4;
    }
}

// ---------------------------------------------------------------------------
// Fallback (round-3 path) if ws too small for msgpre buffer.
// ---------------------------------------------------------------------------
__global__ __launch_bounds__(256) void edge_node(
    const bf16* __restrict__ x,
    const int* __restrict__ erow,
    const void* __restrict__ eattr,
    const bf16* __restrict__ ew,
    const void* __restrict__ eb,
    const void* __restrict__ g1, const void* __restrict__ b1,
    const int* __restrict__ offsets, const int* __restrict__ eid,
    bf16* __restrict__ combined, const int* __restrict__ flag)
{
    __shared__ float part[32][4][2];
    const bool f32 = (*flag != 0);
    const int wave = threadIdx.x >> 6;
    const int lane = threadIdx.x & 63;
    const int quad = lane >> 4;
    const int l16  = lane & 15;
    const int n = blockIdx.x;
    const int start = offsets[n];
    const int cnt   = offsets[n + 1] - start;

    float gv[4], bv[4], ebv[4];
#pragma unroll
    for (int nt = 0; nt < 4; ++nt) {
        int col = wave * 64 + nt * 16 + l16;
        gv[nt]  = ldf(g1, col, f32);
        bv[nt]  = ldf(b1, col, f32);
        ebv[nt] = ldf(eb, col, f32);
    }
    const bf16* wp = ew + (size_t)(wave * 64 + l16) * 768 + quad * 8;
    const bf16* xn = x + (size_t)n * 256 + quad * 8;

    f32x4 acc1[4] = {};
#pragma unroll
    for (int kk = 0; kk < 8; ++kk) {
        bf16x8 a = *(const bf16x8*)(xn + kk * 32);
#pragma unroll
        for (int nt = 0; nt < 4; ++nt) {
            bf16x8 b = *(const bf16x8*)(wp + (size_t)nt * 16 * 768 + 256 + kk * 32);
            acc1[nt] = MFMA16(a, b, acc1[nt]);
        }
    }
    float nacc[4] = {0.f, 0.f, 0.f, 0.f};
    for (int c0 = 0; c0 < cnt; c0 += 32) {
        int i0 = c0 + l16;      i0 = (i0 < cnt) ? i0 : 0;
        int i1 = c0 + 16 + l16; i1 = (i1 < cnt) ? i1 : 0;
        int e0 = eid[start + i0];
        int e1 = eid[start + i1];
        const bf16* xr0 = x + (size_t)erow[e0] * 256 + quad * 8;
        const bf16* xr1 = x + (size_t)erow[e1] * 256 + quad * 8;
        f32x4 acc[2][4];
#pragma unroll
        for (int nt = 0; nt < 4; ++nt) { acc[0][nt] = acc1[nt]; acc[1][nt] = acc1[nt]; }
#pragma unroll
        for (int kk = 0; kk < 8; ++kk) {
            bf16x8 a0 = *(const bf16x8*)(xr0 + kk * 32);
            bf16x8 a1 = *(const bf16x8*)(xr1 + kk * 32);
#pragma unroll
            for (int nt = 0; nt < 4; ++nt) {
                bf16x8 b = *(const bf16x8*)(wp + (size_t)nt * 16 * 768 + kk * 32);
                acc[0][nt] = MFMA16(a0, b, acc[0][nt]);
                acc[1][nt] = MFMA16(a1, b, acc[1][nt]);
            }
        }
#pragma unroll
        for (int kk = 0; kk < 8; ++kk) {
            int koff = quad * 8 + kk * 32;
            bf16x8 a0 = ld8(eattr, (size_t)e0 * 256 + koff, f32);
            bf16x8 a1 = ld8(eattr, (size_t)e1 * 256 + koff, f32);
#pragma unroll
            for (int nt = 0; nt < 4; ++nt) {
                bf16x8 b = *(const bf16x8*)(wp + (size_t)nt * 16 * 768 + 512 + kk * 32);
                acc[0][nt] = MFMA16(a0, b, acc[0][nt]);
                acc[1][nt] = MFMA16(a1, b, acc[1][nt]);
            }
        }
#pragma unroll
        for (int mt = 0; mt < 2; ++mt)
#pragma unroll
            for (int nt = 0; nt < 4; ++nt)
#pragma unroll
                for (int r = 0; r < 4; ++r) acc[mt][nt][r] += ebv[nt];
        float ps[2][4], pq[2][4];
#pragma unroll
        for (int mt = 0; mt < 2; ++mt)
#pragma unroll
            for (int r = 0; r < 4; ++r) {
                float s = 0.f, q = 0.f;
#pragma unroll
                for (int nt = 0; nt < 4; ++nt) {
                    float v = acc[mt][nt][r];
                    s += v; q += v * v;
                }
                ps[mt][r] = s; pq[mt][r] = q;
            }
#pragma unroll
        for (int msk = 1; msk < 16; msk <<= 1)
#pragma unroll
            for (int mt = 0; mt < 2; ++mt)
#pragma unroll
                for (int r = 0; r < 4; ++r) {
                    ps[mt][r] += __shfl_xor(ps[mt][r], msk);
                    pq[mt][r] += __shfl_xor(pq[mt][r], msk);
                }
        if (l16 == 0) {
#pragma unroll
            for (int mt = 0; mt < 2; ++mt)
#pragma unroll
                for (int r = 0; r < 4; ++r) {
                    part[mt * 16 + quad * 4 + r][wave][0] = ps[mt][r];
                    part[mt * 16 + quad * 4 + r][wave][1] = pq[mt][r];
                }
        }
        __syncthreads();
#pragma unroll
        for (int mt = 0; mt < 2; ++mt)
#pragma unroll
            for (int r = 0; r < 4; ++r) {
                int row = mt * 16 + quad * 4 + r;
                float s = part[row][0][0] + part[row][1][0] + part[row][2][0] + part[row][3][0];
                float q = part[row][0][1] + part[row][1][1] + part[row][2][1] + part[row][3][1];
                float mean = s * (1.0f / 256.0f);
                float var  = q * (1.0f / 256.0f) - mean * mean;
                float rstd = rsqrtf(var + 1e-5f);
                if ((c0 + row) < cnt) {
#pragma unroll
                    for (int nt = 0; nt < 4; ++nt) {
                        float val = (acc[mt][nt][r] - mean) * rstd * gv[nt] + bv[nt];
                        nacc[nt] += fmaxf(val, 0.0f);
                    }
                }
            }
        __syncthreads();
    }
#pragma unroll
    for (int nt = 0; nt < 4; ++nt) {
        nacc[nt] += __shfl_xor(nacc[nt], 16);
        nacc[nt] += __shfl_xor(nacc[nt], 32);
    }
    if (quad == 0) {
#pragma unroll
        for (int nt = 0; nt < 4; ++nt)
            combined[(size_t)n * 512 + 256 + wave * 64 + nt * 16 + l16] = (bf16)nacc[nt];
    }
}

// ---------------------------------------------------------------------------
// Fused output projection + bias + residual + LayerNorm2. M=16 rows/block
// (grid 256 = full GPU), K=512.
// ---------------------------------------------------------------------------
__global__ __launch_bounds__(256) void gemm_ln(
    const bf16* __restrict__ A,          // combined [4096][512]
    const bf16* __restrict__ W,          // ow [256][512]
    const void* __restrict__ bias,       // o_b
    const bf16* __restrict__ resid,      // x_bf [4096][256]
    const void* __restrict__ g, const void* __restrict__ bb,
    void* __restrict__ out, const int* __restrict__ flag)
{
    __shared__ float stats[16][4][2];
    const bool f32 = (*flag != 0);
    const int wave = threadIdx.x >> 6;
    const int lane = threadIdx.x & 63;
    const int quad = lane >> 4;
    const int l16  = lane & 15;
    const int m_base = blockIdx.x * 16;

    const bf16* ap = A + (size_t)(m_base + l16) * 512 + quad * 8;
    const bf16* wp = W + (size_t)(wave * 64 + l16) * 512 + quad * 8;

    f32x4 acc[4] = {};
#pragma unroll
    for (int kk = 0; kk < 16; ++kk) {
        int k = kk * 32;
        bf16x8 a = *(const bf16x8*)(ap + k);
#pragma unroll
        for (int nt = 0; nt < 4; ++nt) {
            bf16x8 b = *(const bf16x8*)(wp + (size_t)nt * 16 * 512 + k);
            acc[nt] = MFMA16(a, b, acc[nt]);
        }
    }
    float s[4] = {}, q[4] = {};
#pragma unroll
    for (int nt = 0; nt < 4; ++nt) {
        int col = wave * 64 + nt * 16 + l16;
        float bv = ldf(bias, col, f32);
#pragma unroll
        for (int r = 0; r < 4; ++r) {
            int row = m_base + quad * 4 + r;
            float v = acc[nt][r] + bv + (float)resid[(size_t)row * 256 + col];
            acc[nt][r] = v;
            s[r] += v;
            q[r] = __builtin_fmaf(v, v, q[r]);
        }
    }
#pragma unroll
    for (int msk = 1; msk < 16; msk <<= 1)
#pragma unroll
        for (int r = 0; r < 4; ++r) {
            s[r] += __shfl_xor(s[r], msk);
            q[r] += __shfl_xor(q[r], msk);
        }
    if (l16 == 0) {
#pragma unroll
        for (int r = 0; r < 4; ++r) {
            stats[quad * 4 + r][wave][0] = s[r];
            stats[quad * 4 + r][wave][1] = q[r];
        }
    }
    __syncthreads();
#pragma unroll
    for (int r = 0; r < 4; ++r) {
        int row16 = quad * 4 + r;
        float ss = (stats[row16][0][0] + stats[row16][1][0]) +
                   (stats[row16][2][0] + stats[row16][3][0]);
        float qq = (stats[row16][0][1] + stats[row16][1][1]) +
                   (stats[row16][2][1] + stats[row16][3][1]);
        float mean = ss * (1.0f / 256.0f);
        float var  = qq * (1.0f / 256.0f) - mean * mean;
        float rstd = rsqrtf(var + 1e-5f);
        int row = m_base + row16;
#pragma unroll
        for (int nt = 0; nt < 4; ++nt) {
            int col = wave * 64 + nt * 16 + l16;
            float o = (acc[nt][r] - mean) * rstd * ldf(g, col, f32) + ldf(bb, col, f32);
            if (f32) ((float*)out)[(size_t)row * 256 + col] = o;
            else     ((bf16*)out)[(size_t)row * 256 + col] = (bf16)o;
        }
    }
}

// ---------------------------------------------------------------------------
extern "C" void kernel_launch(void* const* d_in, const int* in_sizes, int n_in,
                              void* d_out, int out_size, void* d_ws, size_t ws_size,
                              hipStream_t stream)
{
    const void* x_raw  = d_in[0];
    const int*  eidx   = (const int*)d_in[1];
    const void* eattr  = d_in[2];
    const void* in_w   = d_in[3];
    const void* in_b   = d_in[4];
    const void* ao_w   = d_in[5];
    const void* ao_b   = d_in[6];
    const void* e_w    = d_in[7];
    const void* e_b    = d_in[8];
    const void* g1     = d_in[9];
    const void* b1     = d_in[10];
    const void* o_w    = d_in[11];
    const void* o_b    = d_in[12];
    const void* g2     = d_in[13];
    const void* b2     = d_in[14];

    char* ws = (char*)d_ws;
    bf16*  qkv      = (bf16*)(ws);               // 6291456 B
    bf16*  vt       = (bf16*)(ws + 6291456);     // 2097152 B
    bf16*  ctx      = (bf16*)(ws + 8388608);     // 2097152 B
    bf16*  combined = (bf16*)(ws + 10485760);    // 4194304 B
    int*   counts   = (int*)(ws + 14680064);     // 16384 B
    int*   offsets  = (int*)(ws + 14696448);     // 16388 B
    int*   cursor   = (int*)(ws + 14712848);     // 16384 B
    int*   eid      = (int*)(ws + 14729232);     // 524288 B
    bf16*  U        = (bf16*)(ws + 18874368);    // 2097152 B
    bf16*  V        = (bf16*)(ws + 20971520);    // 2097152 B
    bf16*  canon    = (bf16*)(ws + 23068672);    // 3276800 B
    int*   flag     = (int*)(ws + 26345472);     // 4 B
    bf16*  msgpre   = (bf16*)(ws + 26345728);    // 67108864 B -> end 93454592

    const size_t WS_NEEDED = 93454592;

    bf16* x_bf   = canon;
    bf16* inw_bf = canon + 1048576;
    bf16* aow_bf = canon + 1245184;
    bf16* ew_bf  = canon + 1310720;
    bf16* ow_bf  = canon + 1507328;

    const int* erow = eidx;
    const int* ecol = eidx + E_EDGES;

    detect_dtype<<<dim3(1), 64, 0, stream>>>(x_raw, flag);
    convert_inputs<<<dim3(6400), 256, 0, stream>>>(x_raw, in_w, ao_w, e_w, o_w,
                                                   canon, flag);
    // CSR build
    hipMemsetAsync(counts, 0, 16384, stream);
    edge_hist<<<dim3(E_EDGES / 256), 256, 0, stream>>>(ecol, counts);
    edge_scan<<<dim3(1), 256, 0, stream>>>(counts, offsets, cursor);
    edge_scatter<<<dim3(E_EDGES / 256), 256, 0, stream>>>(ecol, cursor, eid);

    // node-level precomputes for the edge MLP: U = x@W0^T, V = x@W1^T (1 launch)
    gemm_uv<<<dim3(128, 2), 256, 0, stream>>>(x_bf, ew_bf, U, V);

    // qkv = x @ in_proj_w^T + in_proj_b
    gemm_bt<<<dim3(128, 3), 256, 0, stream>>>(x_bf, 256, inw_bf, 256, in_b,
                                              qkv, 768, 0, nullptr, 0, 256, flag);
    transpose_v<<<dim3(64, 8), 256, 0, stream>>>(qkv, vt);
    attn_kernel<<<dim3(1024), 256, 0, stream>>>(qkv, vt, ctx);
    gemm_bt<<<dim3(128, 1), 256, 0, stream>>>(ctx, 256, aow_bf, 256, ao_b,
                                              combined, 512, 0, nullptr, 0, 256, flag);
    if (ws_size >= WS_NEEDED) {
        // stage 1: streaming GEMM, flat-coalesced in and out (natural order)
        edge_gemm<<<dim3(E_EDGES / 64), 256, 0, stream>>>(eattr, ew_bf, e_b,
                                                          msgpre, flag);
        // stage 2: per-node LN+ReLU+sum, gathering msgpre[eid[pos]]
        node_ln<<<dim3(N_NODES), 256, 0, stream>>>(msgpre, offsets, eid, erow,
                                                   U, V, g1, b1, combined, flag);
    } else {
        edge_node<<<dim3(N_NODES), 256, 0, stream>>>(x_bf, erow, eattr,
                                                     ew_bf, e_b, g1, b1,
                                                     offsets, eid, combined, flag);
    }
    // fused out-proj + residual + LN2 -> d_out
    gemm_ln<<<dim3(256), 256, 0, stream>>>(combined, ow_bf, o_b, x_bf,
                                           g2, b2, d_out, flag);
}